// Round 16
// baseline (294.973 us; speedup 1.0000x reference)
//
#include <hip/hip_runtime.h>

constexpr int Bc = 4;     // batch
constexpr int Cc = 256;   // channels
constexpr int Dc = 64;    // q/k dim
constexpr int Nc = 4096;  // sequence length

typedef __attribute__((ext_vector_type(8))) _Float16 f16x8;
typedef __attribute__((ext_vector_type(4))) _Float16 f16x4;
typedef __attribute__((ext_vector_type(4))) float f32x4;

__device__ inline float exp2fast(float x) { return __builtin_amdgcn_exp2f(x); }

// async 16B global->LDS (wave-uniform LDS base, per-lane global addr)
__device__ inline void gload_lds16(const _Float16* g, _Float16* lds) {
  __builtin_amdgcn_global_load_lds(
      (const __attribute__((address_space(1))) unsigned int*)g,
      (__attribute__((address_space(3))) unsigned int*)lds, 16, 0, 0);
}

// ---------------------------------------------------------------------------
// weights -> fp16. z: 0..3 = {w_vx,w_vy,w_tx,w_ty} (C*C), 4..5 = {w_qkx,w_qky}
// ---------------------------------------------------------------------------
__global__ __launch_bounds__(256) void wconv_kernel(
    const float* __restrict__ Wvx, const float* __restrict__ Wvy,
    const float* __restrict__ Wtx, const float* __restrict__ Wty,
    const float* __restrict__ Wqkx, const float* __restrict__ Wqky,
    _Float16* __restrict__ Wh)
{
  const int i = blockIdx.x * 256 + threadIdx.x;
  const int z = blockIdx.y;
  if (z < 4) {
    const float* w = (z == 0) ? Wvx : (z == 1) ? Wvy : (z == 2) ? Wtx : Wty;
    Wh[(size_t)z * Cc * Cc + i] = (_Float16)w[i];
  } else if (i < Dc * Cc) {
    const float* w = (z == 4) ? Wqkx : Wqky;
    Wh[(size_t)4 * Cc * Cc + (size_t)(z - 4) * Dc * Cc + i] = (_Float16)w[i];
  }
}

// ---------------------------------------------------------------------------
// transpose-cast: x,y fp32 [b][c][n] -> Xt fp16 [src][b][n][c]
// grid (Nc/64, Cc/64, 8 {src,b})
// ---------------------------------------------------------------------------
__global__ __launch_bounds__(256) void transpose_kernel(
    const float* __restrict__ X, const float* __restrict__ Y,
    _Float16* __restrict__ Xt)
{
  __shared__ float tile[64][65];
  const int t  = threadIdx.x;
  const int n0 = blockIdx.x * 64;
  const int c0 = blockIdx.y * 64;
  const int z  = blockIdx.z, br = z >> 2, b = z & 3;
  const float* In = (br ? Y : X) + (size_t)b * Cc * Nc;
#pragma unroll
  for (int p = 0; p < 4; ++p) {
    const int c = p * 16 + (t >> 4), n4 = (t & 15) * 4;
    float4 v = *(const float4*)&In[(size_t)(c0 + c) * Nc + n0 + n4];
    tile[c][n4 + 0] = v.x; tile[c][n4 + 1] = v.y;
    tile[c][n4 + 2] = v.z; tile[c][n4 + 3] = v.w;
  }
  __syncthreads();
  _Float16* Ob = Xt + ((size_t)(br * Bc + b) * Nc + n0) * Cc + c0;
#pragma unroll
  for (int p = 0; p < 4; ++p) {
    const int n = p * 16 + (t >> 4), c4 = (t & 15) * 4;
    f16x4 w;
#pragma unroll
    for (int j = 0; j < 4; ++j) w[j] = (_Float16)tile[c4 + j][n];
    *(f16x4*)&Ob[(size_t)n * Cc + c4] = w;
  }
}

// ---------------------------------------------------------------------------
// q/k conv via MFMA: Out[n][d] = sum_c Wqk[d][c] * Xt[n][c]
// Q is scaled by log2(e) so attention softmax can use exp2 directly.
// K rows PRE-SWIZZLED (half-off ^= (n&7)<<3). grid (Nc/128, 2 {q,k}, 8)
// ---------------------------------------------------------------------------
__global__ __launch_bounds__(256, 4) void conv_qk_mfma_kernel(
    const _Float16* __restrict__ Xt, const _Float16* __restrict__ Wh,
    _Float16* __restrict__ Qt, _Float16* __restrict__ Kt)
{
  const int t  = threadIdx.x;
  const int ws = t >> 6, l = t & 63, lr = l & 15, lg = l >> 4;
  const int n_w = blockIdx.x * 128 + ws * 32;
  const int qk = blockIdx.y;
  const int z  = blockIdx.z, br = z >> 2, b = z & 3;
  const size_t bb = (size_t)(br * Bc + b);
  const int insel = (qk ^ br ^ 1) & 1;   // 0=x, 1=y
  _Float16* Out = qk ? Kt : Qt;
  const float scale = qk ? 1.0f : 1.44269504088896f;

  const _Float16* wbase = Wh + (size_t)4 * Cc * Cc + (size_t)br * Dc * Cc
                          + (size_t)lr * Cc + lg * 8;
  const _Float16* xbase = Xt + ((size_t)(insel * Bc + b) * Nc + n_w + lr) * Cc + lg * 8;

  f32x4 acc[4][2] = {};  // [dt][nt]
  for (int c0 = 0; c0 < Cc; c0 += 32) {
    f16x8 wf[4], xf[2];
#pragma unroll
    for (int dt = 0; dt < 4; ++dt)
      wf[dt] = *(const f16x8*)(wbase + (size_t)(dt * 16) * Cc + c0);
#pragma unroll
    for (int nt = 0; nt < 2; ++nt)
      xf[nt] = *(const f16x8*)(xbase + (size_t)(nt * 16) * Cc + c0);
#pragma unroll
    for (int dt = 0; dt < 4; ++dt)
#pragma unroll
      for (int nt = 0; nt < 2; ++nt)
        acc[dt][nt] = __builtin_amdgcn_mfma_f32_16x16x32_f16(wf[dt], xf[nt], acc[dt][nt], 0, 0, 0);
  }
#pragma unroll
  for (int dt = 0; dt < 4; ++dt)
#pragma unroll
    for (int nt = 0; nt < 2; ++nt) {
      const int n  = n_w + nt * 16 + lr;
      const int d0 = dt * 16 + lg * 4;
      const int off = qk ? (d0 ^ ((n & 7) << 3)) : d0;
      f16x4 o4;
#pragma unroll
      for (int r = 0; r < 4; ++r) o4[r] = (_Float16)(acc[dt][nt][r] * scale);
      *(f16x4*)&Out[(bb * Nc + n) * 64 + off] = o4;
    }
}

// ---------------------------------------------------------------------------
// v conv via MFMA: V[cout][n] = sum_c Wv[cout][c] * Xt[n][c]
// grid (Nc/128, Cc/128, 8), block 256 (2x2 wave grid)
// ---------------------------------------------------------------------------
__global__ __launch_bounds__(256, 4) void conv_v_mfma_kernel(
    const _Float16* __restrict__ Xt, const _Float16* __restrict__ Wh,
    _Float16* __restrict__ Vb)
{
  const int t  = threadIdx.x;
  const int ws = t >> 6, l = t & 63, lr = l & 15, lg = l >> 4;
  const int wm = ws >> 1, wo = ws & 1;
  const int n_w = blockIdx.x * 128 + wm * 64;
  const int o_w = blockIdx.y * 128 + wo * 64;
  const int z  = blockIdx.z, br = z >> 2, b = z & 3;
  const size_t bb = (size_t)(br * Bc + b);

  const _Float16* abase = Xt + (bb * Nc + n_w + lr) * Cc + lg * 8;
  const _Float16* bbase = Wh + ((size_t)br * Cc + o_w + lr) * Cc + lg * 8;
  f32x4 acc[4][4] = {};  // [ot][mt]

  for (int c0 = 0; c0 < Cc; c0 += 32) {
    f16x8 af[4], bfr[4];
#pragma unroll
    for (int mt = 0; mt < 4; ++mt)
      af[mt] = *(const f16x8*)(abase + (size_t)(mt * 16) * Cc + c0);
#pragma unroll
    for (int ot = 0; ot < 4; ++ot)
      bfr[ot] = *(const f16x8*)(bbase + (size_t)(ot * 16) * Cc + c0);
#pragma unroll
    for (int ot = 0; ot < 4; ++ot)
#pragma unroll
      for (int mt = 0; mt < 4; ++mt)
        acc[ot][mt] = __builtin_amdgcn_mfma_f32_16x16x32_f16(af[mt], bfr[ot], acc[ot][mt], 0, 0, 0);
  }
#pragma unroll
  for (int ot = 0; ot < 4; ++ot)
#pragma unroll
    for (int mt = 0; mt < 4; ++mt) {
      const int cout = o_w + ot * 16 + lr;
      const int n = n_w + mt * 16 + lg * 4;
      f16x4 o4;
#pragma unroll
      for (int r = 0; r < 4; ++r) o4[r] = (_Float16)acc[ot][mt][r];
      *(f16x4*)&Vb[(bb * Cc + cout) * Nc + n] = o4;
    }
}

// ---------------------------------------------------------------------------
// MFMA flash attention, wave-specialized, KVBLK=128 (fp16, exp2):
// block = 768 threads (12 waves). Producers ws 0-3: K staging (16KB/chunk) +
// QK (st[8], 16 MFMA) + defer-max softmax + P (64x128) writes. Consumers
// ws 4-11: 32-channel strip each, V prefetch vf[2][2][4] (parity dbuf) +
// 32 PV MFMAs/chunk. Half the barrier iterations of the KVBLK=64 version.
// grid (Nc/64, nsp, 2*B).
// ---------------------------------------------------------------------------
__global__ __launch_bounds__(768, 3) void attn_mfma_kernel(
    const _Float16* __restrict__ Qt,   // [2B][N][64], pre-scaled by log2(e)
    const _Float16* __restrict__ Kt,   // [2B][N][64] pre-swizzled rows
    const _Float16* __restrict__ V,    // [2B][C][N]
    _Float16* __restrict__ Op,         // [2B][nsp][N][C] partial O
    float* __restrict__ Ml,            // [2B][nsp][N][2] (m, l in log2 domain)
    int nsp, int kn)
{
  __shared__ __align__(16) _Float16 k_lds[2][128 * 64];  // 2 x 16KB
  __shared__ __align__(16) _Float16 p_lds[2][64 * 128];  // 2 x 16KB
  __shared__ float s_fac[2][64];

  const int t  = threadIdx.x;
  const int ws = t >> 6;          // 0..11
  const int l  = t & 63;
  const int lr = l & 15;
  const int lg = l >> 4;

  const int nwg  = (Nc / 64) * nsp * 8;
  const int lin  = blockIdx.x + gridDim.x * (blockIdx.y + gridDim.y * blockIdx.z);
  const int work = (lin & 7) * (nwg >> 3) + (lin >> 3);
  const int m0   = (work & 63) * 64;
  const int spbb = work >> 6;
  const int sp   = spbb % nsp;
  const size_t bb = (size_t)(spbb / nsp);

  const _Float16* kgl = Kt + (bb * Nc + (size_t)sp * kn) * 64;
  const int nch = kn >> 7;   // 128-key chunks; 16 (nsp=2) or 32 (nsp=1), even

  if (ws < 4) {
    // ================= PRODUCER: QK + softmax =================
    const _Float16* qp = Qt + (bb * Nc + m0 + ws * 16 + lr) * 64 + lg * 8;
    const f16x8 qf0 = *(const f16x8*)qp;
    const f16x8 qf1 = *(const f16x8*)(qp + 32);
    const _Float16* gq = kgl + ws * 2048 + l * 8;

    float m_run = -1e30f, l_run = 0.f;   // per-lane partial l
    const int mrow = ws * 16 + lr;
    const int sw   = (mrow & 7) << 4;

    {  // prologue: chunk 0 (16KB) -> k_lds[0]
#pragma unroll
      for (int r = 0; r < 4; ++r)
        gload_lds16(gq + r * 512, &k_lds[0][ws * 2048 + r * 512]);
    }
    __syncthreads();

    for (int ch2 = 0; ch2 < nch; ch2 += 2) {
#pragma unroll
      for (int par = 0; par < 2; ++par) {
        const int ch = ch2 + par;
        // stage K(ch+1) into k_lds[par^1]
        if (ch + 1 < nch) {
          const _Float16* g = gq + (size_t)(ch + 1) * (128 * 64);
#pragma unroll
          for (int r = 0; r < 4; ++r)
            gload_lds16(g + r * 512, &k_lds[par ^ 1][ws * 2048 + r * 512]);
        }
        // QK^T for chunk ch from k_lds[par] (128 keys -> st[8])
        f32x4 st[8];
#pragma unroll
        for (int nt = 0; nt < 8; ++nt) st[nt] = f32x4{0.f, 0.f, 0.f, 0.f};
#pragma unroll
        for (int nt = 0; nt < 8; ++nt) {
          const int   krow = nt * 16 + lr;
          const char* krp  = (const char*)&k_lds[par][krow * 64];
          const int   swr  = (krow & 7) << 4;
          f16x8 kh0 = *(const f16x8*)(krp + ((lg * 16) ^ swr));
          f16x8 kh1 = *(const f16x8*)(krp + ((64 + lg * 16) ^ swr));
          st[nt] = __builtin_amdgcn_mfma_f32_16x16x32_f16(kh0, qf0, st[nt], 0, 0, 0);
          st[nt] = __builtin_amdgcn_mfma_f32_16x16x32_f16(kh1, qf1, st[nt], 0, 0, 0);
        }
        // defer-max softmax (zero cross-lane steady state)
        float mx = st[0][0];
#pragma unroll
        for (int nt = 0; nt < 8; ++nt)
#pragma unroll
          for (int rr = 0; rr < 4; ++rr) mx = fmaxf(mx, st[nt][rr]);
        float s = 1.0f;
        if (__any(mx > m_run + 12.0f)) {
          mx = fmaxf(mx, __shfl_xor(mx, 16));
          mx = fmaxf(mx, __shfl_xor(mx, 32));
          const float mnew = fmaxf(m_run, mx);
          s = exp2fast(m_run - mnew);
          m_run = mnew;
        }
        float sum = 0.f;
#pragma unroll
        for (int nt = 0; nt < 8; ++nt) {
          float p0 = exp2fast(st[nt][0] - m_run);
          float p1 = exp2fast(st[nt][1] - m_run);
          float p2 = exp2fast(st[nt][2] - m_run);
          float p3 = exp2fast(st[nt][3] - m_run);
          sum += p0 + p1 + p2 + p3;
          f16x4 pb;
          pb[0] = (_Float16)p0; pb[1] = (_Float16)p1;
          pb[2] = (_Float16)p2; pb[3] = (_Float16)p3;
          char* prow = (char*)&p_lds[par][mrow * 128];
          *(f16x4*)(prow + ((nt * 32 + lg * 8) ^ sw)) = pb;
        }
        l_run = l_run * s + sum;
        if (lg == 0) s_fac[par][ws * 16 + lr] = s;
        __syncthreads();
      }
    }

    // epilogue: reduce per-lane partial l, write stats
    l_run += __shfl_xor(l_run, 16);
    l_run += __shfl_xor(l_run, 32);
    if (lg == 0) {
      size_t mi = ((bb * nsp + sp) * Nc + m0 + ws * 16 + lr) * 2;
      Ml[mi]     = m_run;
      Ml[mi + 1] = l_run;
    }
  } else {
    // ================= CONSUMER: PV (32-channel strip per wave) ============
    const int cw = ws - 4;   // 0..7
    const _Float16* vbase = V + (bb * Cc + cw * 32 + lr) * Nc + sp * kn + lg * 8;
    f32x4 acc[2][4] = {};
    f16x8 vf[2][2][4];   // [parity][ct][kk]

    __syncthreads();   // match producer prologue barrier

    for (int ch2 = 0; ch2 < nch; ch2 += 2) {
#pragma unroll
      for (int par = 0; par < 2; ++par) {
        const int ch = ch2 + par;
        // V prefetch for chunk ch (consumed next sub-iter)
        {
          const _Float16* vp = vbase + ch * 128;
#pragma unroll
          for (int ct = 0; ct < 2; ++ct)
#pragma unroll
            for (int kk = 0; kk < 4; ++kk)
              vf[par][ct][kk] = *(const f16x8*)(vp + (size_t)ct * 16 * Nc + kk * 32);
        }
        // PV for chunk ch-1 (p_lds/s_fac from par^1; vf[par^1])
        if (ch > 0) {
          float scm[4];
#pragma unroll
          for (int mt = 0; mt < 4; ++mt) scm[mt] = s_fac[par ^ 1][mt * 16 + lr];
          const int needs = (scm[0] != 1.f) | (scm[1] != 1.f) |
                            (scm[2] != 1.f) | (scm[3] != 1.f);
          if (__any(needs)) {
#pragma unroll
            for (int ct = 0; ct < 2; ++ct)
#pragma unroll
              for (int mt = 0; mt < 4; ++mt) {
                acc[ct][mt][0] *= scm[mt]; acc[ct][mt][1] *= scm[mt];
                acc[ct][mt][2] *= scm[mt]; acc[ct][mt][3] *= scm[mt];
              }
          }
          f16x8 pf[4][4];
#pragma unroll
          for (int mt = 0; mt < 4; ++mt) {
            const int   rm  = mt * 16 + lr;
            const char* pr  = (const char*)&p_lds[par ^ 1][rm * 128];
            const int   swr = (rm & 7) << 4;
#pragma unroll
            for (int kk = 0; kk < 4; ++kk)
              pf[mt][kk] = *(const f16x8*)(pr + ((lg * 16 + kk * 64) ^ swr));
          }
          __builtin_amdgcn_s_setprio(1);
#pragma unroll
          for (int ct = 0; ct < 2; ++ct)
#pragma unroll
            for (int kk = 0; kk < 4; ++kk)
#pragma unroll
              for (int mt = 0; mt < 4; ++mt)
                acc[ct][mt] = __builtin_amdgcn_mfma_f32_16x16x32_f16(vf[par ^ 1][ct][kk], pf[mt][kk], acc[ct][mt], 0, 0, 0);
          __builtin_amdgcn_s_setprio(0);
        }
        __syncthreads();
      }
    }

    // epilogue PV (last chunk: parity 1, nch even)
    {
      float scm[4];
#pragma unroll
      for (int mt = 0; mt < 4; ++mt) scm[mt] = s_fac[1][mt * 16 + lr];
      const int needs = (scm[0] != 1.f) | (scm[1] != 1.f) |
                        (scm[2] != 1.f) | (scm[3] != 1.f);
      if (__any(needs)) {
#pragma unroll
        for (int ct = 0; ct < 2; ++ct)
#pragma unroll
          for (int mt = 0; mt < 4; ++mt) {
            acc[ct][mt][0] *= scm[mt]; acc[ct][mt][1] *= scm[mt];
            acc[ct][mt][2] *= scm[mt]; acc[ct][mt][3] *= scm[mt];
          }
      }
      f16x8 pf[4][4];
#pragma unroll
      for (int mt = 0; mt < 4; ++mt) {
        const int   rm  = mt * 16 + lr;
        const char* pr  = (const char*)&p_lds[1][rm * 128];
        const int   swr = (rm & 7) << 4;
#pragma unroll
        for (int kk = 0; kk < 4; ++kk)
          pf[mt][kk] = *(const f16x8*)(pr + ((lg * 16 + kk * 64) ^ swr));
      }
#pragma unroll
      for (int ct = 0; ct < 2; ++ct)
#pragma unroll
        for (int kk = 0; kk < 4; ++kk)
#pragma unroll
          for (int mt = 0; mt < 4; ++mt)
            acc[ct][mt] = __builtin_amdgcn_mfma_f32_16x16x32_f16(vf[1][ct][kk], pf[mt][kk], acc[ct][mt], 0, 0, 0);
    }

    // write unnormalized partial O as [m][c] (c-contiguous)
    _Float16* ob = Op + (bb * nsp + sp) * (size_t)Cc * Nc;
#pragma unroll
    for (int ct = 0; ct < 2; ++ct)
#pragma unroll
      for (int mt = 0; mt < 4; ++mt) {
        const int c0 = cw * 32 + ct * 16 + lg * 4;
        const int m  = m0 + mt * 16 + lr;
        f16x4 o4;
#pragma unroll
        for (int r = 0; r < 4; ++r) o4[r] = (_Float16)acc[ct][mt][r];
        *(f16x4*)&ob[(size_t)m * Cc + c0] = o4;
      }
  }
}

// ---------------------------------------------------------------------------
// Combine partials -> normalized r, fp16 [2B][m][c]. m,l are log2-domain.
// ---------------------------------------------------------------------------
__global__ __launch_bounds__(256) void combine_kernel(
    const _Float16* __restrict__ Op, const float* __restrict__ Ml,
    _Float16* __restrict__ Rt, int nsp)
{
  const int tid = blockIdx.x * 256 + threadIdx.x;
  const int c0 = (tid & 63) * 4;
  const int m  = (tid >> 6) & (Nc - 1);
  const int bb = tid >> 18;
  float val[4];
  if (nsp == 2) {
    const _Float16* o0 = Op + ((size_t)bb * 2 + 0) * Cc * Nc + (size_t)m * Cc + c0;
    const _Float16* o1 = Op + ((size_t)bb * 2 + 1) * Cc * Nc + (size_t)m * Cc + c0;
    const float* ml0 = Ml + (((size_t)bb * 2 + 0) * Nc + m) * 2;
    const float* ml1 = Ml + (((size_t)bb * 2 + 1) * Nc + m) * 2;
    float m1 = ml0[0], L1 = ml0[1], m2 = ml1[0], L2 = ml1[1];
    float M  = fmaxf(m1, m2);
    float w1 = __builtin_amdgcn_exp2f(m1 - M), w2 = __builtin_amdgcn_exp2f(m2 - M);
    float inv = 1.0f / (w1 * L1 + w2 * L2);
    f16x4 a = *(const f16x4*)o0;
    f16x4 d = *(const f16x4*)o1;
#pragma unroll
    for (int j = 0; j < 4; ++j) val[j] = (w1 * (float)a[j] + w2 * (float)d[j]) * inv;
  } else {
    const _Float16* o0 = Op + (size_t)bb * Cc * Nc + (size_t)m * Cc + c0;
    const float* ml0 = Ml + ((size_t)bb * Nc + m) * 2;
    float inv = 1.0f / ml0[1];
    f16x4 a = *(const f16x4*)o0;
#pragma unroll
    for (int j = 0; j < 4; ++j) val[j] = (float)a[j] * inv;
  }
  f16x4 r4;
#pragma unroll
  for (int j = 0; j < 4; ++j) r4[j] = (_Float16)val[j];
  *(f16x4*)&Rt[((size_t)bb * Nc + m) * Cc + c0] = r4;
}

// ---------------------------------------------------------------------------
// t = w_t @ r via MFMA -> Th fp16 [2B][o][m], plus per-block BN partial sums
// (partials from exact fp32 accumulators). grid (Nc/128, Cc/128, 8)
// ---------------------------------------------------------------------------
__global__ __launch_bounds__(256, 4) void conv_t_mfma_kernel(
    const _Float16* __restrict__ Rt, const _Float16* __restrict__ Wh,
    _Float16* __restrict__ Th, float* __restrict__ part)
{
  __shared__ float red[2][2][4][16][2];
  const int t  = threadIdx.x;
  const int ws = t >> 6, l = t & 63, lr = l & 15, lg = l >> 4;
  const int wm = ws >> 1, wo = ws & 1;
  const int m_w = blockIdx.x * 128 + wm * 64;
  const int o_w = blockIdx.y * 128 + wo * 64;
  const int z  = blockIdx.z, br = z >> 2, b = z & 3;
  const size_t bb = (size_t)(br * Bc + b);

  const _Float16* abase = Rt + (bb * Nc + m_w + lr) * Cc + lg * 8;
  const _Float16* bbase = Wh + ((size_t)(2 + br) * Cc + o_w + lr) * Cc + lg * 8;
  f32x4 acc[4][4] = {};  // [ot][mt]

  for (int c0 = 0; c0 < Cc; c0 += 32) {
    f16x8 af[4], bfr[4];
#pragma unroll
    for (int mt = 0; mt < 4; ++mt)
      af[mt] = *(const f16x8*)(abase + (size_t)(mt * 16) * Cc + c0);
#pragma unroll
    for (int ot = 0; ot < 4; ++ot)
      bfr[ot] = *(const f16x8*)(bbase + (size_t)(ot * 16) * Cc + c0);
#pragma unroll
    for (int ot = 0; ot < 4; ++ot)
#pragma unroll
      for (int mt = 0; mt < 4; ++mt)
        acc[ot][mt] = __builtin_amdgcn_mfma_f32_16x16x32_f16(af[mt], bfr[ot], acc[ot][mt], 0, 0, 0);
  }
  _Float16* Tb = Th + bb * Cc * Nc;
#pragma unroll
  for (int ot = 0; ot < 4; ++ot) {
    float s = 0.f, q = 0.f;
#pragma unroll
    for (int mt = 0; mt < 4; ++mt) {
      const int o = o_w + ot * 16 + lr;
      const int m = m_w + mt * 16 + lg * 4;
      f16x4 h4;
#pragma unroll
      for (int r = 0; r < 4; ++r) {
        float v = acc[ot][mt][r];
        h4[r] = (_Float16)v;
        s += v; q += v * v;
      }
      *(f16x4*)&Tb[(size_t)o * Nc + m] = h4;
    }
    s += __shfl_xor(s, 16); s += __shfl_xor(s, 32);
    q += __shfl_xor(q, 16); q += __shfl_xor(q, 32);
    if (lg == 0) { red[wm][wo][ot][lr][0] = s; red[wm][wo][ot][lr][1] = q; }
  }
  __syncthreads();
  {
    const int wo2 = t >> 7, ot2 = (t >> 5) & 3, lr2 = (t >> 1) & 15, kind = t & 1;
    float v = red[0][wo2][ot2][lr2][kind] + red[1][wo2][ot2][lr2][kind];
    const int c = blockIdx.y * 128 + wo2 * 64 + ot2 * 16 + lr2;
    const int slot = blockIdx.x * 4 + b;
    part[(((size_t)br * Cc + c) * 128 + slot) * 2 + kind] = v;
  }
}

// ---------------------------------------------------------------------------
// finalize BN stats: mean / istd per (br, channel)
// ---------------------------------------------------------------------------
__global__ __launch_bounds__(256) void bn_finalize_kernel(
    const float* __restrict__ part, float* __restrict__ stats)
{
  const int br = blockIdx.x, c = threadIdx.x;
  const float* p = part + ((size_t)br * Cc + c) * 128 * 2;
  float s = 0.f, q = 0.f;
#pragma unroll 4
  for (int i = 0; i < 128; ++i) { s += p[i * 2]; q += p[i * 2 + 1]; }
  const float inv_n = 1.0f / (float)(Bc * Nc);
  const float mean = s * inv_n;
  const float var  = q * inv_n - mean * mean;
  stats[(br * 2 + 0) * Cc + c] = mean;
  stats[(br * 2 + 1) * Cc + c] = rsqrtf(var + 1e-5f);
}

// ---------------------------------------------------------------------------
// Epilogue: OUT = SRC + relu(bn(Th)) -> d_out (fp32)
// ---------------------------------------------------------------------------
__global__ __launch_bounds__(256) void bn_out_kernel(
    const _Float16* __restrict__ Th, float* __restrict__ OUT,
    const float* __restrict__ X, const float* __restrict__ Y,
    const float* __restrict__ stats, const float* __restrict__ gamma,
    const float* __restrict__ beta)
{
  const int br = blockIdx.y;
  const int i = blockIdx.x * 256 + threadIdx.x;
  const size_t flat = ((size_t)i << 2);
  const int c = (int)((flat >> 12) & (Cc - 1));
  float mean = stats[(br * 2 + 0) * Cc + c], istd = stats[(br * 2 + 1) * Cc + c];
  float gm = gamma[c], bt = beta[c];
  const _Float16* Tb = Th + (size_t)br * Bc * Cc * Nc;
  float* Ob = OUT + (size_t)br * Bc * Cc * Nc;
  const float* SRC = (br ? Y : X);
  f16x4 t4 = *(const f16x4*)&Tb[flat];
  float4 s4 = *(const float4*)&SRC[flat];
  float4 o4;
  o4.x = s4.x + fmaxf(0.f, gm * ((float)t4[0] - mean) * istd + bt);
  o4.y = s4.y + fmaxf(0.f, gm * ((float)t4[1] - mean) * istd + bt);
  o4.z = s4.z + fmaxf(0.f, gm * ((float)t4[2] - mean) * istd + bt);
  o4.w = s4.w + fmaxf(0.f, gm * ((float)t4[3] - mean) * istd + bt);
  *(float4*)&Ob[flat] = o4;
}

// ---------------------------------------------------------------------------
extern "C" void kernel_launch(void* const* d_in, const int* in_sizes, int n_in,
                              void* d_out, int out_size, void* d_ws, size_t ws_size,
                              hipStream_t stream) {
  const float* x     = (const float*)d_in[0];
  const float* y     = (const float*)d_in[1];
  const float* w_qkx = (const float*)d_in[2];
  const float* w_vx  = (const float*)d_in[3];
  const float* w_tx  = (const float*)d_in[4];
  const float* w_qky = (const float*)d_in[5];
  const float* w_vy  = (const float*)d_in[6];
  const float* w_ty  = (const float*)d_in[7];
  const float* gamma = (const float*)d_in[8];
  const float* beta  = (const float*)d_in[9];

  float* out = (float*)d_out;  // [2][B][C][N]

  const int nsp = (ws_size >= 60ull * 1024 * 1024) ? 2 : 1;
  const int kn  = Nc / nsp;

  char* wsb = (char*)d_ws;
  _Float16* qt = (_Float16*)wsb;                        // 4 MB [2B][N][64]
  _Float16* kt = (_Float16*)(wsb + (4ull << 20));       // 4 MB (pre-swizzled)
  _Float16* vb = (_Float16*)(wsb + (8ull << 20));       // 16 MB [2B][C][N]
  _Float16* xt = (_Float16*)(wsb + (24ull << 20));      // 16 MB [2][B][N][C]
  _Float16* op = (_Float16*)(wsb + (24ull << 20));      // nsp*16 MB (overlays xt)
  size_t off = (24ull << 20) + (size_t)nsp * (16ull << 20);
  float* ml = (float*)(wsb + off);                      // nsp*256 KB
  off += (size_t)nsp * (256ull << 10);
  _Float16* wh = (_Float16*)(wsb + off);                // 576 KB weights fp16
  off += (640ull << 10);
  float* part = (float*)(wsb + off);                    // 512 KB partial sums
  off += (512ull << 10);
  float* st = (float*)(wsb + off);                      // 8 KB stats
  _Float16* rt = (_Float16*)wsb;                        // 16 MB, overlays qt/kt/vb-head
  _Float16* th = (_Float16*)(wsb + (24ull << 20));      // 17 MB, overlays op (dead after combine)

  wconv_kernel<<<dim3(Cc * Cc / 256, 6), 256, 0, stream>>>(w_vx, w_vy, w_tx, w_ty, w_qkx, w_qky, wh);
  transpose_kernel<<<dim3(Nc / 64, Cc / 64, 8), 256, 0, stream>>>(x, y, xt);
  conv_qk_mfma_kernel<<<dim3(Nc / 128, 2, 8), 256, 0, stream>>>(xt, wh, qt, kt);
  conv_v_mfma_kernel<<<dim3(Nc / 128, Cc / 128, 8), 256, 0, stream>>>(xt, wh, vb);
  attn_mfma_kernel<<<dim3(Nc / 64, nsp, 8), 768, 0, stream>>>(qt, kt, vb, op, ml, nsp, kn);
  combine_kernel<<<(2 * Bc * Nc * (Cc / 4)) / 256, 256, 0, stream>>>(op, ml, rt, nsp);
  conv_t_mfma_kernel<<<dim3(Nc / 128, Cc / 128, 8), 256, 0, stream>>>(rt, wh, th, part);
  bn_finalize_kernel<<<2, 256, 0, stream>>>(part, st);
  bn_out_kernel<<<dim3((Bc * Cc * Nc / 4) / 256, 2), 256, 0, stream>>>(th, out, x, y, st, gamma, beta);
}

// Round 17
// 294.671 us; speedup vs baseline: 1.0010x; 1.0010x over previous
//
#include <hip/hip_runtime.h>

constexpr int Bc = 4;     // batch
constexpr int Cc = 256;   // channels
constexpr int Dc = 64;    // q/k dim
constexpr int Nc = 4096;  // sequence length

typedef __attribute__((ext_vector_type(8))) _Float16 f16x8;
typedef __attribute__((ext_vector_type(4))) _Float16 f16x4;
typedef __attribute__((ext_vector_type(4))) float f32x4;

__device__ inline float exp2fast(float x) { return __builtin_amdgcn_exp2f(x); }

// async 16B global->LDS (wave-uniform LDS base, per-lane global addr)
__device__ inline void gload_lds16(const _Float16* g, _Float16* lds) {
  __builtin_amdgcn_global_load_lds(
      (const __attribute__((address_space(1))) unsigned int*)g,
      (__attribute__((address_space(3))) unsigned int*)lds, 16, 0, 0);
}

// ---------------------------------------------------------------------------
// weights -> fp16. z: 0..3 = {w_vx,w_vy,w_tx,w_ty} (C*C), 4..5 = {w_qkx,w_qky}
// ---------------------------------------------------------------------------
__global__ __launch_bounds__(256) void wconv_kernel(
    const float* __restrict__ Wvx, const float* __restrict__ Wvy,
    const float* __restrict__ Wtx, const float* __restrict__ Wty,
    const float* __restrict__ Wqkx, const float* __restrict__ Wqky,
    _Float16* __restrict__ Wh)
{
  const int i = blockIdx.x * 256 + threadIdx.x;
  const int z = blockIdx.y;
  if (z < 4) {
    const float* w = (z == 0) ? Wvx : (z == 1) ? Wvy : (z == 2) ? Wtx : Wty;
    Wh[(size_t)z * Cc * Cc + i] = (_Float16)w[i];
  } else if (i < Dc * Cc) {
    const float* w = (z == 4) ? Wqkx : Wqky;
    Wh[(size_t)4 * Cc * Cc + (size_t)(z - 4) * Dc * Cc + i] = (_Float16)w[i];
  }
}

// ---------------------------------------------------------------------------
// transpose-cast: x,y fp32 [b][c][n] -> Xt fp16 [src][b][n][c]
// grid (Nc/64, Cc/64, 8 {src,b})
// ---------------------------------------------------------------------------
__global__ __launch_bounds__(256) void transpose_kernel(
    const float* __restrict__ X, const float* __restrict__ Y,
    _Float16* __restrict__ Xt)
{
  __shared__ float tile[64][65];
  const int t  = threadIdx.x;
  const int n0 = blockIdx.x * 64;
  const int c0 = blockIdx.y * 64;
  const int z  = blockIdx.z, br = z >> 2, b = z & 3;
  const float* In = (br ? Y : X) + (size_t)b * Cc * Nc;
#pragma unroll
  for (int p = 0; p < 4; ++p) {
    const int c = p * 16 + (t >> 4), n4 = (t & 15) * 4;
    float4 v = *(const float4*)&In[(size_t)(c0 + c) * Nc + n0 + n4];
    tile[c][n4 + 0] = v.x; tile[c][n4 + 1] = v.y;
    tile[c][n4 + 2] = v.z; tile[c][n4 + 3] = v.w;
  }
  __syncthreads();
  _Float16* Ob = Xt + ((size_t)(br * Bc + b) * Nc + n0) * Cc + c0;
#pragma unroll
  for (int p = 0; p < 4; ++p) {
    const int n = p * 16 + (t >> 4), c4 = (t & 15) * 4;
    f16x4 w;
#pragma unroll
    for (int j = 0; j < 4; ++j) w[j] = (_Float16)tile[c4 + j][n];
    *(f16x4*)&Ob[(size_t)n * Cc + c4] = w;
  }
}

// ---------------------------------------------------------------------------
// q/k conv via MFMA: Out[n][d] = sum_c Wqk[d][c] * Xt[n][c]
// Q is scaled by log2(e) so attention softmax can use exp2 directly.
// K rows PRE-SWIZZLED (half-off ^= (n&7)<<3). grid (Nc/128, 2 {q,k}, 8)
// ---------------------------------------------------------------------------
__global__ __launch_bounds__(256, 4) void conv_qk_mfma_kernel(
    const _Float16* __restrict__ Xt, const _Float16* __restrict__ Wh,
    _Float16* __restrict__ Qt, _Float16* __restrict__ Kt)
{
  const int t  = threadIdx.x;
  const int ws = t >> 6, l = t & 63, lr = l & 15, lg = l >> 4;
  const int n_w = blockIdx.x * 128 + ws * 32;
  const int qk = blockIdx.y;
  const int z  = blockIdx.z, br = z >> 2, b = z & 3;
  const size_t bb = (size_t)(br * Bc + b);
  const int insel = (qk ^ br ^ 1) & 1;   // 0=x, 1=y
  _Float16* Out = qk ? Kt : Qt;
  const float scale = qk ? 1.0f : 1.44269504088896f;

  const _Float16* wbase = Wh + (size_t)4 * Cc * Cc + (size_t)br * Dc * Cc
                          + (size_t)lr * Cc + lg * 8;
  const _Float16* xbase = Xt + ((size_t)(insel * Bc + b) * Nc + n_w + lr) * Cc + lg * 8;

  f32x4 acc[4][2] = {};  // [dt][nt]
  for (int c0 = 0; c0 < Cc; c0 += 32) {
    f16x8 wf[4], xf[2];
#pragma unroll
    for (int dt = 0; dt < 4; ++dt)
      wf[dt] = *(const f16x8*)(wbase + (size_t)(dt * 16) * Cc + c0);
#pragma unroll
    for (int nt = 0; nt < 2; ++nt)
      xf[nt] = *(const f16x8*)(xbase + (size_t)(nt * 16) * Cc + c0);
#pragma unroll
    for (int dt = 0; dt < 4; ++dt)
#pragma unroll
      for (int nt = 0; nt < 2; ++nt)
        acc[dt][nt] = __builtin_amdgcn_mfma_f32_16x16x32_f16(wf[dt], xf[nt], acc[dt][nt], 0, 0, 0);
  }
#pragma unroll
  for (int dt = 0; dt < 4; ++dt)
#pragma unroll
    for (int nt = 0; nt < 2; ++nt) {
      const int n  = n_w + nt * 16 + lr;
      const int d0 = dt * 16 + lg * 4;
      const int off = qk ? (d0 ^ ((n & 7) << 3)) : d0;
      f16x4 o4;
#pragma unroll
      for (int r = 0; r < 4; ++r) o4[r] = (_Float16)(acc[dt][nt][r] * scale);
      *(f16x4*)&Out[(bb * Nc + n) * 64 + off] = o4;
    }
}

// ---------------------------------------------------------------------------
// v conv via MFMA: V[cout][n] = sum_c Wv[cout][c] * Xt[n][c]
// grid (Nc/128, Cc/128, 8), block 256 (2x2 wave grid)
// ---------------------------------------------------------------------------
__global__ __launch_bounds__(256, 4) void conv_v_mfma_kernel(
    const _Float16* __restrict__ Xt, const _Float16* __restrict__ Wh,
    _Float16* __restrict__ Vb)
{
  const int t  = threadIdx.x;
  const int ws = t >> 6, l = t & 63, lr = l & 15, lg = l >> 4;
  const int wm = ws >> 1, wo = ws & 1;
  const int n_w = blockIdx.x * 128 + wm * 64;
  const int o_w = blockIdx.y * 128 + wo * 64;
  const int z  = blockIdx.z, br = z >> 2, b = z & 3;
  const size_t bb = (size_t)(br * Bc + b);

  const _Float16* abase = Xt + (bb * Nc + n_w + lr) * Cc + lg * 8;
  const _Float16* bbase = Wh + ((size_t)br * Cc + o_w + lr) * Cc + lg * 8;
  f32x4 acc[4][4] = {};  // [ot][mt]

  for (int c0 = 0; c0 < Cc; c0 += 32) {
    f16x8 af[4], bfr[4];
#pragma unroll
    for (int mt = 0; mt < 4; ++mt)
      af[mt] = *(const f16x8*)(abase + (size_t)(mt * 16) * Cc + c0);
#pragma unroll
    for (int ot = 0; ot < 4; ++ot)
      bfr[ot] = *(const f16x8*)(bbase + (size_t)(ot * 16) * Cc + c0);
#pragma unroll
    for (int ot = 0; ot < 4; ++ot)
#pragma unroll
      for (int mt = 0; mt < 4; ++mt)
        acc[ot][mt] = __builtin_amdgcn_mfma_f32_16x16x32_f16(af[mt], bfr[ot], acc[ot][mt], 0, 0, 0);
  }
#pragma unroll
  for (int ot = 0; ot < 4; ++ot)
#pragma unroll
    for (int mt = 0; mt < 4; ++mt) {
      const int cout = o_w + ot * 16 + lr;
      const int n = n_w + mt * 16 + lg * 4;
      f16x4 o4;
#pragma unroll
      for (int r = 0; r < 4; ++r) o4[r] = (_Float16)acc[ot][mt][r];
      *(f16x4*)&Vb[(bb * Cc + cout) * Nc + n] = o4;
    }
}

// ---------------------------------------------------------------------------
// MFMA flash attention, wave-specialized, KVBLK=128 (fp16, exp2):
// block = 768 threads (12 waves). Producers ws 0-3: K staging (16KB/chunk) +
// QK (st[8], 16 MFMA) + defer-max softmax + P (64x128) writes. Consumers
// ws 4-11: 32-channel strip each, V prefetch vf[2][2][4] (parity dbuf) +
// 32 PV MFMAs/chunk. Half the barrier iterations of the KVBLK=64 version.
// grid (Nc/64, nsp, 2*B).
// ---------------------------------------------------------------------------
__global__ __launch_bounds__(768, 3) void attn_mfma_kernel(
    const _Float16* __restrict__ Qt,   // [2B][N][64], pre-scaled by log2(e)
    const _Float16* __restrict__ Kt,   // [2B][N][64] pre-swizzled rows
    const _Float16* __restrict__ V,    // [2B][C][N]
    _Float16* __restrict__ Op,         // [2B][nsp][N][C] partial O
    float* __restrict__ Ml,            // [2B][nsp][N][2] (m, l in log2 domain)
    int nsp, int kn)
{
  __shared__ __align__(16) _Float16 k_lds[2][128 * 64];  // 2 x 16KB
  __shared__ __align__(16) _Float16 p_lds[2][64 * 128];  // 2 x 16KB
  __shared__ float s_fac[2][64];

  const int t  = threadIdx.x;
  const int ws = t >> 6;          // 0..11
  const int l  = t & 63;
  const int lr = l & 15;
  const int lg = l >> 4;

  const int nwg  = (Nc / 64) * nsp * 8;
  const int lin  = blockIdx.x + gridDim.x * (blockIdx.y + gridDim.y * blockIdx.z);
  const int work = (lin & 7) * (nwg >> 3) + (lin >> 3);
  const int m0   = (work & 63) * 64;
  const int spbb = work >> 6;
  const int sp   = spbb % nsp;
  const size_t bb = (size_t)(spbb / nsp);

  const _Float16* kgl = Kt + (bb * Nc + (size_t)sp * kn) * 64;
  const int nch = kn >> 7;   // 128-key chunks; 16 (nsp=2) or 32 (nsp=1), even

  if (ws < 4) {
    // ================= PRODUCER: QK + softmax =================
    const _Float16* qp = Qt + (bb * Nc + m0 + ws * 16 + lr) * 64 + lg * 8;
    const f16x8 qf0 = *(const f16x8*)qp;
    const f16x8 qf1 = *(const f16x8*)(qp + 32);
    const _Float16* gq = kgl + ws * 2048 + l * 8;

    float m_run = -1e30f, l_run = 0.f;   // per-lane partial l
    const int mrow = ws * 16 + lr;
    const int sw   = (mrow & 7) << 4;

    {  // prologue: chunk 0 (16KB) -> k_lds[0]
#pragma unroll
      for (int r = 0; r < 4; ++r)
        gload_lds16(gq + r * 512, &k_lds[0][ws * 2048 + r * 512]);
    }
    __syncthreads();

    for (int ch2 = 0; ch2 < nch; ch2 += 2) {
#pragma unroll
      for (int par = 0; par < 2; ++par) {
        const int ch = ch2 + par;
        // stage K(ch+1) into k_lds[par^1]
        if (ch + 1 < nch) {
          const _Float16* g = gq + (size_t)(ch + 1) * (128 * 64);
#pragma unroll
          for (int r = 0; r < 4; ++r)
            gload_lds16(g + r * 512, &k_lds[par ^ 1][ws * 2048 + r * 512]);
        }
        // QK^T for chunk ch from k_lds[par] (128 keys -> st[8])
        f32x4 st[8];
#pragma unroll
        for (int nt = 0; nt < 8; ++nt) st[nt] = f32x4{0.f, 0.f, 0.f, 0.f};
#pragma unroll
        for (int nt = 0; nt < 8; ++nt) {
          const int   krow = nt * 16 + lr;
          const char* krp  = (const char*)&k_lds[par][krow * 64];
          const int   swr  = (krow & 7) << 4;
          f16x8 kh0 = *(const f16x8*)(krp + ((lg * 16) ^ swr));
          f16x8 kh1 = *(const f16x8*)(krp + ((64 + lg * 16) ^ swr));
          st[nt] = __builtin_amdgcn_mfma_f32_16x16x32_f16(kh0, qf0, st[nt], 0, 0, 0);
          st[nt] = __builtin_amdgcn_mfma_f32_16x16x32_f16(kh1, qf1, st[nt], 0, 0, 0);
        }
        // defer-max softmax (zero cross-lane steady state)
        float mx = st[0][0];
#pragma unroll
        for (int nt = 0; nt < 8; ++nt)
#pragma unroll
          for (int rr = 0; rr < 4; ++rr) mx = fmaxf(mx, st[nt][rr]);
        float s = 1.0f;
        if (__any(mx > m_run + 12.0f)) {
          mx = fmaxf(mx, __shfl_xor(mx, 16));
          mx = fmaxf(mx, __shfl_xor(mx, 32));
          const float mnew = fmaxf(m_run, mx);
          s = exp2fast(m_run - mnew);
          m_run = mnew;
        }
        float sum = 0.f;
#pragma unroll
        for (int nt = 0; nt < 8; ++nt) {
          float p0 = exp2fast(st[nt][0] - m_run);
          float p1 = exp2fast(st[nt][1] - m_run);
          float p2 = exp2fast(st[nt][2] - m_run);
          float p3 = exp2fast(st[nt][3] - m_run);
          sum += p0 + p1 + p2 + p3;
          f16x4 pb;
          pb[0] = (_Float16)p0; pb[1] = (_Float16)p1;
          pb[2] = (_Float16)p2; pb[3] = (_Float16)p3;
          char* prow = (char*)&p_lds[par][mrow * 128];
          *(f16x4*)(prow + ((nt * 32 + lg * 8) ^ sw)) = pb;
        }
        l_run = l_run * s + sum;
        if (lg == 0) s_fac[par][ws * 16 + lr] = s;
        __syncthreads();
      }
    }

    // epilogue: reduce per-lane partial l, write stats
    l_run += __shfl_xor(l_run, 16);
    l_run += __shfl_xor(l_run, 32);
    if (lg == 0) {
      size_t mi = ((bb * nsp + sp) * Nc + m0 + ws * 16 + lr) * 2;
      Ml[mi]     = m_run;
      Ml[mi + 1] = l_run;
    }
  } else {
    // ================= CONSUMER: PV (32-channel strip per wave) ============
    const int cw = ws - 4;   // 0..7
    const _Float16* vbase = V + (bb * Cc + cw * 32 + lr) * Nc + sp * kn + lg * 8;
    f32x4 acc[2][4] = {};
    f16x8 vf[2][2][4];   // [parity][ct][kk]

    __syncthreads();   // match producer prologue barrier

    for (int ch2 = 0; ch2 < nch; ch2 += 2) {
#pragma unroll
      for (int par = 0; par < 2; ++par) {
        const int ch = ch2 + par;
        // V prefetch for chunk ch (consumed next sub-iter)
        {
          const _Float16* vp = vbase + ch * 128;
#pragma unroll
          for (int ct = 0; ct < 2; ++ct)
#pragma unroll
            for (int kk = 0; kk < 4; ++kk)
              vf[par][ct][kk] = *(const f16x8*)(vp + (size_t)ct * 16 * Nc + kk * 32);
        }
        // PV for chunk ch-1 (p_lds/s_fac from par^1; vf[par^1])
        if (ch > 0) {
          float scm[4];
#pragma unroll
          for (int mt = 0; mt < 4; ++mt) scm[mt] = s_fac[par ^ 1][mt * 16 + lr];
          const int needs = (scm[0] != 1.f) | (scm[1] != 1.f) |
                            (scm[2] != 1.f) | (scm[3] != 1.f);
          if (__any(needs)) {
#pragma unroll
            for (int ct = 0; ct < 2; ++ct)
#pragma unroll
              for (int mt = 0; mt < 4; ++mt) {
                acc[ct][mt][0] *= scm[mt]; acc[ct][mt][1] *= scm[mt];
                acc[ct][mt][2] *= scm[mt]; acc[ct][mt][3] *= scm[mt];
              }
          }
          f16x8 pf[4][4];
#pragma unroll
          for (int mt = 0; mt < 4; ++mt) {
            const int   rm  = mt * 16 + lr;
            const char* pr  = (const char*)&p_lds[par ^ 1][rm * 128];
            const int   swr = (rm & 7) << 4;
#pragma unroll
            for (int kk = 0; kk < 4; ++kk)
              pf[mt][kk] = *(const f16x8*)(pr + ((lg * 16 + kk * 64) ^ swr));
          }
          __builtin_amdgcn_s_setprio(1);
#pragma unroll
          for (int ct = 0; ct < 2; ++ct)
#pragma unroll
            for (int kk = 0; kk < 4; ++kk)
#pragma unroll
              for (int mt = 0; mt < 4; ++mt)
                acc[ct][mt] = __builtin_amdgcn_mfma_f32_16x16x32_f16(vf[par ^ 1][ct][kk], pf[mt][kk], acc[ct][mt], 0, 0, 0);
          __builtin_amdgcn_s_setprio(0);
        }
        __syncthreads();
      }
    }

    // epilogue PV (last chunk: parity 1, nch even)
    {
      float scm[4];
#pragma unroll
      for (int mt = 0; mt < 4; ++mt) scm[mt] = s_fac[1][mt * 16 + lr];
      const int needs = (scm[0] != 1.f) | (scm[1] != 1.f) |
                        (scm[2] != 1.f) | (scm[3] != 1.f);
      if (__any(needs)) {
#pragma unroll
        for (int ct = 0; ct < 2; ++ct)
#pragma unroll
          for (int mt = 0; mt < 4; ++mt) {
            acc[ct][mt][0] *= scm[mt]; acc[ct][mt][1] *= scm[mt];
            acc[ct][mt][2] *= scm[mt]; acc[ct][mt][3] *= scm[mt];
          }
      }
      f16x8 pf[4][4];
#pragma unroll
      for (int mt = 0; mt < 4; ++mt) {
        const int   rm  = mt * 16 + lr;
        const char* pr  = (const char*)&p_lds[1][rm * 128];
        const int   swr = (rm & 7) << 4;
#pragma unroll
        for (int kk = 0; kk < 4; ++kk)
          pf[mt][kk] = *(const f16x8*)(pr + ((lg * 16 + kk * 64) ^ swr));
      }
#pragma unroll
      for (int ct = 0; ct < 2; ++ct)
#pragma unroll
        for (int kk = 0; kk < 4; ++kk)
#pragma unroll
          for (int mt = 0; mt < 4; ++mt)
            acc[ct][mt] = __builtin_amdgcn_mfma_f32_16x16x32_f16(vf[1][ct][kk], pf[mt][kk], acc[ct][mt], 0, 0, 0);
    }

    // write unnormalized partial O as [m][c] (c-contiguous)
    _Float16* ob = Op + (bb * nsp + sp) * (size_t)Cc * Nc;
#pragma unroll
    for (int ct = 0; ct < 2; ++ct)
#pragma unroll
      for (int mt = 0; mt < 4; ++mt) {
        const int c0 = cw * 32 + ct * 16 + lg * 4;
        const int m  = m0 + mt * 16 + lr;
        f16x4 o4;
#pragma unroll
        for (int r = 0; r < 4; ++r) o4[r] = (_Float16)acc[ct][mt][r];
        *(f16x4*)&ob[(size_t)m * Cc + c0] = o4;
      }
  }
}

// ---------------------------------------------------------------------------
// Combine partials -> normalized r, fp16 [2B][m][c]. m,l are log2-domain.
// ---------------------------------------------------------------------------
__global__ __launch_bounds__(256) void combine_kernel(
    const _Float16* __restrict__ Op, const float* __restrict__ Ml,
    _Float16* __restrict__ Rt, int nsp)
{
  const int tid = blockIdx.x * 256 + threadIdx.x;
  const int c0 = (tid & 63) * 4;
  const int m  = (tid >> 6) & (Nc - 1);
  const int bb = tid >> 18;
  float val[4];
  if (nsp == 2) {
    const _Float16* o0 = Op + ((size_t)bb * 2 + 0) * Cc * Nc + (size_t)m * Cc + c0;
    const _Float16* o1 = Op + ((size_t)bb * 2 + 1) * Cc * Nc + (size_t)m * Cc + c0;
    const float* ml0 = Ml + (((size_t)bb * 2 + 0) * Nc + m) * 2;
    const float* ml1 = Ml + (((size_t)bb * 2 + 1) * Nc + m) * 2;
    float m1 = ml0[0], L1 = ml0[1], m2 = ml1[0], L2 = ml1[1];
    float M  = fmaxf(m1, m2);
    float w1 = __builtin_amdgcn_exp2f(m1 - M), w2 = __builtin_amdgcn_exp2f(m2 - M);
    float inv = 1.0f / (w1 * L1 + w2 * L2);
    f16x4 a = *(const f16x4*)o0;
    f16x4 d = *(const f16x4*)o1;
#pragma unroll
    for (int j = 0; j < 4; ++j) val[j] = (w1 * (float)a[j] + w2 * (float)d[j]) * inv;
  } else {
    const _Float16* o0 = Op + (size_t)bb * Cc * Nc + (size_t)m * Cc + c0;
    const float* ml0 = Ml + ((size_t)bb * Nc + m) * 2;
    float inv = 1.0f / ml0[1];
    f16x4 a = *(const f16x4*)o0;
#pragma unroll
    for (int j = 0; j < 4; ++j) val[j] = (float)a[j] * inv;
  }
  f16x4 r4;
#pragma unroll
  for (int j = 0; j < 4; ++j) r4[j] = (_Float16)val[j];
  *(f16x4*)&Rt[((size_t)bb * Nc + m) * Cc + c0] = r4;
}

// ---------------------------------------------------------------------------
// t = w_t @ r via MFMA -> Th fp16 [2B][o][m], plus per-block BN partial sums
// (partials from exact fp32 accumulators). grid (Nc/128, Cc/128, 8)
// ---------------------------------------------------------------------------
__global__ __launch_bounds__(256, 4) void conv_t_mfma_kernel(
    const _Float16* __restrict__ Rt, const _Float16* __restrict__ Wh,
    _Float16* __restrict__ Th, float* __restrict__ part)
{
  __shared__ float red[2][2][4][16][2];
  const int t  = threadIdx.x;
  const int ws = t >> 6, l = t & 63, lr = l & 15, lg = l >> 4;
  const int wm = ws >> 1, wo = ws & 1;
  const int m_w = blockIdx.x * 128 + wm * 64;
  const int o_w = blockIdx.y * 128 + wo * 64;
  const int z  = blockIdx.z, br = z >> 2, b = z & 3;
  const size_t bb = (size_t)(br * Bc + b);

  const _Float16* abase = Rt + (bb * Nc + m_w + lr) * Cc + lg * 8;
  const _Float16* bbase = Wh + ((size_t)(2 + br) * Cc + o_w + lr) * Cc + lg * 8;
  f32x4 acc[4][4] = {};  // [ot][mt]

  for (int c0 = 0; c0 < Cc; c0 += 32) {
    f16x8 af[4], bfr[4];
#pragma unroll
    for (int mt = 0; mt < 4; ++mt)
      af[mt] = *(const f16x8*)(abase + (size_t)(mt * 16) * Cc + c0);
#pragma unroll
    for (int ot = 0; ot < 4; ++ot)
      bfr[ot] = *(const f16x8*)(bbase + (size_t)(ot * 16) * Cc + c0);
#pragma unroll
    for (int ot = 0; ot < 4; ++ot)
#pragma unroll
      for (int mt = 0; mt < 4; ++mt)
        acc[ot][mt] = __builtin_amdgcn_mfma_f32_16x16x32_f16(af[mt], bfr[ot], acc[ot][mt], 0, 0, 0);
  }
  _Float16* Tb = Th + bb * Cc * Nc;
#pragma unroll
  for (int ot = 0; ot < 4; ++ot) {
    float s = 0.f, q = 0.f;
#pragma unroll
    for (int mt = 0; mt < 4; ++mt) {
      const int o = o_w + ot * 16 + lr;
      const int m = m_w + mt * 16 + lg * 4;
      f16x4 h4;
#pragma unroll
      for (int r = 0; r < 4; ++r) {
        float v = acc[ot][mt][r];
        h4[r] = (_Float16)v;
        s += v; q += v * v;
      }
      *(f16x4*)&Tb[(size_t)o * Nc + m] = h4;
    }
    s += __shfl_xor(s, 16); s += __shfl_xor(s, 32);
    q += __shfl_xor(q, 16); q += __shfl_xor(q, 32);
    if (lg == 0) { red[wm][wo][ot][lr][0] = s; red[wm][wo][ot][lr][1] = q; }
  }
  __syncthreads();
  {
    const int wo2 = t >> 7, ot2 = (t >> 5) & 3, lr2 = (t >> 1) & 15, kind = t & 1;
    float v = red[0][wo2][ot2][lr2][kind] + red[1][wo2][ot2][lr2][kind];
    const int c = blockIdx.y * 128 + wo2 * 64 + ot2 * 16 + lr2;
    const int slot = blockIdx.x * 4 + b;
    part[(((size_t)br * Cc + c) * 128 + slot) * 2 + kind] = v;
  }
}

// ---------------------------------------------------------------------------
// finalize BN stats: mean / istd per (br, channel)
// ---------------------------------------------------------------------------
__global__ __launch_bounds__(256) void bn_finalize_kernel(
    const float* __restrict__ part, float* __restrict__ stats)
{
  const int br = blockIdx.x, c = threadIdx.x;
  const float* p = part + ((size_t)br * Cc + c) * 128 * 2;
  float s = 0.f, q = 0.f;
#pragma unroll 4
  for (int i = 0; i < 128; ++i) { s += p[i * 2]; q += p[i * 2 + 1]; }
  const float inv_n = 1.0f / (float)(Bc * Nc);
  const float mean = s * inv_n;
  const float var  = q * inv_n - mean * mean;
  stats[(br * 2 + 0) * Cc + c] = mean;
  stats[(br * 2 + 1) * Cc + c] = rsqrtf(var + 1e-5f);
}

// ---------------------------------------------------------------------------
// Epilogue: OUT = SRC + relu(bn(Th)) -> d_out (fp32)
// ---------------------------------------------------------------------------
__global__ __launch_bounds__(256) void bn_out_kernel(
    const _Float16* __restrict__ Th, float* __restrict__ OUT,
    const float* __restrict__ X, const float* __restrict__ Y,
    const float* __restrict__ stats, const float* __restrict__ gamma,
    const float* __restrict__ beta)
{
  const int br = blockIdx.y;
  const int i = blockIdx.x * 256 + threadIdx.x;
  const size_t flat = ((size_t)i << 2);
  const int c = (int)((flat >> 12) & (Cc - 1));
  float mean = stats[(br * 2 + 0) * Cc + c], istd = stats[(br * 2 + 1) * Cc + c];
  float gm = gamma[c], bt = beta[c];
  const _Float16* Tb = Th + (size_t)br * Bc * Cc * Nc;
  float* Ob = OUT + (size_t)br * Bc * Cc * Nc;
  const float* SRC = (br ? Y : X);
  f16x4 t4 = *(const f16x4*)&Tb[flat];
  float4 s4 = *(const float4*)&SRC[flat];
  float4 o4;
  o4.x = s4.x + fmaxf(0.f, gm * ((float)t4[0] - mean) * istd + bt);
  o4.y = s4.y + fmaxf(0.f, gm * ((float)t4[1] - mean) * istd + bt);
  o4.z = s4.z + fmaxf(0.f, gm * ((float)t4[2] - mean) * istd + bt);
  o4.w = s4.w + fmaxf(0.f, gm * ((float)t4[3] - mean) * istd + bt);
  *(float4*)&Ob[flat] = o4;
}

// ---------------------------------------------------------------------------
extern "C" void kernel_launch(void* const* d_in, const int* in_sizes, int n_in,
                              void* d_out, int out_size, void* d_ws, size_t ws_size,
                              hipStream_t stream) {
  const float* x     = (const float*)d_in[0];
  const float* y     = (const float*)d_in[1];
  const float* w_qkx = (const float*)d_in[2];
  const float* w_vx  = (const float*)d_in[3];
  const float* w_tx  = (const float*)d_in[4];
  const float* w_qky = (const float*)d_in[5];
  const float* w_vy  = (const float*)d_in[6];
  const float* w_ty  = (const float*)d_in[7];
  const float* gamma = (const float*)d_in[8];
  const float* beta  = (const float*)d_in[9];

  float* out = (float*)d_out;  // [2][B][C][N]

  const int nsp = (ws_size >= 60ull * 1024 * 1024) ? 2 : 1;
  const int kn  = Nc / nsp;

  char* wsb = (char*)d_ws;
  _Float16* qt = (_Float16*)wsb;                        // 4 MB [2B][N][64]
  _Float16* kt = (_Float16*)(wsb + (4ull << 20));       // 4 MB (pre-swizzled)
  _Float16* vb = (_Float16*)(wsb + (8ull << 20));       // 16 MB [2B][C][N]
  _Float16* xt = (_Float16*)(wsb + (24ull << 20));      // 16 MB [2][B][N][C]
  _Float16* op = (_Float16*)(wsb + (24ull << 20));      // nsp*16 MB (overlays xt)
  size_t off = (24ull << 20) + (size_t)nsp * (16ull << 20);
  float* ml = (float*)(wsb + off);                      // nsp*256 KB
  off += (size_t)nsp * (256ull << 10);
  _Float16* wh = (_Float16*)(wsb + off);                // 576 KB weights fp16
  off += (640ull << 10);
  float* part = (float*)(wsb + off);                    // 512 KB partial sums
  off += (512ull << 10);
  float* st = (float*)(wsb + off);                      // 8 KB stats
  _Float16* rt = (_Float16*)wsb;                        // 16 MB, overlays qt/kt/vb-head
  _Float16* th = (_Float16*)(wsb + (24ull << 20));      // 17 MB, overlays op (dead after combine)

  wconv_kernel<<<dim3(Cc * Cc / 256, 6), 256, 0, stream>>>(w_vx, w_vy, w_tx, w_ty, w_qkx, w_qky, wh);
  transpose_kernel<<<dim3(Nc / 64, Cc / 64, 8), 256, 0, stream>>>(x, y, xt);
  conv_qk_mfma_kernel<<<dim3(Nc / 128, 2, 8), 256, 0, stream>>>(xt, wh, qt, kt);
  conv_v_mfma_kernel<<<dim3(Nc / 128, Cc / 128, 8), 256, 0, stream>>>(xt, wh, vb);
  attn_mfma_kernel<<<dim3(Nc / 64, nsp, 8), 768, 0, stream>>>(qt, kt, vb, op, ml, nsp, kn);
  combine_kernel<<<(2 * Bc * Nc * (Cc / 4)) / 256, 256, 0, stream>>>(op, ml, rt, nsp);
  conv_t_mfma_kernel<<<dim3(Nc / 128, Cc / 128, 8), 256, 0, stream>>>(rt, wh, th, part);
  bn_finalize_kernel<<<2, 256, 0, stream>>>(part, st);
  bn_out_kernel<<<dim3((Bc * Cc * Nc / 4) / 256, 2), 256, 0, stream>>>(th, out, x, y, st, gamma, beta);
}

// Round 18
// 266.798 us; speedup vs baseline: 1.1056x; 1.1045x over previous
//
#include <hip/hip_runtime.h>

constexpr int Bc = 4;     // batch
constexpr int Cc = 256;   // channels
constexpr int Dc = 64;    // q/k dim
constexpr int Nc = 4096;  // sequence length

typedef __attribute__((ext_vector_type(8))) _Float16 f16x8;
typedef __attribute__((ext_vector_type(4))) _Float16 f16x4;
typedef __attribute__((ext_vector_type(4))) float f32x4;

__device__ inline float exp2fast(float x) { return __builtin_amdgcn_exp2f(x); }

// async 16B global->LDS (wave-uniform LDS base, per-lane global addr)
__device__ inline void gload_lds16(const _Float16* g, _Float16* lds) {
  __builtin_amdgcn_global_load_lds(
      (const __attribute__((address_space(1))) unsigned int*)g,
      (__attribute__((address_space(3))) unsigned int*)lds, 16, 0, 0);
}

// ---------------------------------------------------------------------------
// weights -> fp16. z: 0..3 = {w_vx,w_vy,w_tx,w_ty} (C*C), 4..5 = {w_qkx,w_qky}
// ---------------------------------------------------------------------------
__global__ __launch_bounds__(256) void wconv_kernel(
    const float* __restrict__ Wvx, const float* __restrict__ Wvy,
    const float* __restrict__ Wtx, const float* __restrict__ Wty,
    const float* __restrict__ Wqkx, const float* __restrict__ Wqky,
    _Float16* __restrict__ Wh)
{
  const int i = blockIdx.x * 256 + threadIdx.x;
  const int z = blockIdx.y;
  if (z < 4) {
    const float* w = (z == 0) ? Wvx : (z == 1) ? Wvy : (z == 2) ? Wtx : Wty;
    Wh[(size_t)z * Cc * Cc + i] = (_Float16)w[i];
  } else if (i < Dc * Cc) {
    const float* w = (z == 4) ? Wqkx : Wqky;
    Wh[(size_t)4 * Cc * Cc + (size_t)(z - 4) * Dc * Cc + i] = (_Float16)w[i];
  }
}

// ---------------------------------------------------------------------------
// transpose-cast: x,y fp32 [b][c][n] -> Xt fp16 [src][b][n][c]
// grid (Nc/64, Cc/64, 8 {src,b})
// ---------------------------------------------------------------------------
__global__ __launch_bounds__(256) void transpose_kernel(
    const float* __restrict__ X, const float* __restrict__ Y,
    _Float16* __restrict__ Xt)
{
  __shared__ float tile[64][65];
  const int t  = threadIdx.x;
  const int n0 = blockIdx.x * 64;
  const int c0 = blockIdx.y * 64;
  const int z  = blockIdx.z, br = z >> 2, b = z & 3;
  const float* In = (br ? Y : X) + (size_t)b * Cc * Nc;
#pragma unroll
  for (int p = 0; p < 4; ++p) {
    const int c = p * 16 + (t >> 4), n4 = (t & 15) * 4;
    float4 v = *(const float4*)&In[(size_t)(c0 + c) * Nc + n0 + n4];
    tile[c][n4 + 0] = v.x; tile[c][n4 + 1] = v.y;
    tile[c][n4 + 2] = v.z; tile[c][n4 + 3] = v.w;
  }
  __syncthreads();
  _Float16* Ob = Xt + ((size_t)(br * Bc + b) * Nc + n0) * Cc + c0;
#pragma unroll
  for (int p = 0; p < 4; ++p) {
    const int n = p * 16 + (t >> 4), c4 = (t & 15) * 4;
    f16x4 w;
#pragma unroll
    for (int j = 0; j < 4; ++j) w[j] = (_Float16)tile[c4 + j][n];
    *(f16x4*)&Ob[(size_t)n * Cc + c4] = w;
  }
}

// ---------------------------------------------------------------------------
// q/k conv via MFMA: Out[n][d] = sum_c Wqk[d][c] * Xt[n][c]
// Q is scaled by log2(e) so attention softmax can use exp2 directly.
// K rows PRE-SWIZZLED (half-off ^= (n&7)<<3). grid (Nc/128, 2 {q,k}, 8)
// ---------------------------------------------------------------------------
__global__ __launch_bounds__(256, 4) void conv_qk_mfma_kernel(
    const _Float16* __restrict__ Xt, const _Float16* __restrict__ Wh,
    _Float16* __restrict__ Qt, _Float16* __restrict__ Kt)
{
  const int t  = threadIdx.x;
  const int ws = t >> 6, l = t & 63, lr = l & 15, lg = l >> 4;
  const int n_w = blockIdx.x * 128 + ws * 32;
  const int qk = blockIdx.y;
  const int z  = blockIdx.z, br = z >> 2, b = z & 3;
  const size_t bb = (size_t)(br * Bc + b);
  const int insel = (qk ^ br ^ 1) & 1;   // 0=x, 1=y
  _Float16* Out = qk ? Kt : Qt;
  const float scale = qk ? 1.0f : 1.44269504088896f;

  const _Float16* wbase = Wh + (size_t)4 * Cc * Cc + (size_t)br * Dc * Cc
                          + (size_t)lr * Cc + lg * 8;
  const _Float16* xbase = Xt + ((size_t)(insel * Bc + b) * Nc + n_w + lr) * Cc + lg * 8;

  f32x4 acc[4][2] = {};  // [dt][nt]
  for (int c0 = 0; c0 < Cc; c0 += 32) {
    f16x8 wf[4], xf[2];
#pragma unroll
    for (int dt = 0; dt < 4; ++dt)
      wf[dt] = *(const f16x8*)(wbase + (size_t)(dt * 16) * Cc + c0);
#pragma unroll
    for (int nt = 0; nt < 2; ++nt)
      xf[nt] = *(const f16x8*)(xbase + (size_t)(nt * 16) * Cc + c0);
#pragma unroll
    for (int dt = 0; dt < 4; ++dt)
#pragma unroll
      for (int nt = 0; nt < 2; ++nt)
        acc[dt][nt] = __builtin_amdgcn_mfma_f32_16x16x32_f16(wf[dt], xf[nt], acc[dt][nt], 0, 0, 0);
  }
#pragma unroll
  for (int dt = 0; dt < 4; ++dt)
#pragma unroll
    for (int nt = 0; nt < 2; ++nt) {
      const int n  = n_w + nt * 16 + lr;
      const int d0 = dt * 16 + lg * 4;
      const int off = qk ? (d0 ^ ((n & 7) << 3)) : d0;
      f16x4 o4;
#pragma unroll
      for (int r = 0; r < 4; ++r) o4[r] = (_Float16)(acc[dt][nt][r] * scale);
      *(f16x4*)&Out[(bb * Nc + n) * 64 + off] = o4;
    }
}

// ---------------------------------------------------------------------------
// v conv via MFMA: V[cout][n] = sum_c Wv[cout][c] * Xt[n][c]
// grid (Nc/128, Cc/128, 8), block 256 (2x2 wave grid)
// ---------------------------------------------------------------------------
__global__ __launch_bounds__(256, 4) void conv_v_mfma_kernel(
    const _Float16* __restrict__ Xt, const _Float16* __restrict__ Wh,
    _Float16* __restrict__ Vb)
{
  const int t  = threadIdx.x;
  const int ws = t >> 6, l = t & 63, lr = l & 15, lg = l >> 4;
  const int wm = ws >> 1, wo = ws & 1;
  const int n_w = blockIdx.x * 128 + wm * 64;
  const int o_w = blockIdx.y * 128 + wo * 64;
  const int z  = blockIdx.z, br = z >> 2, b = z & 3;
  const size_t bb = (size_t)(br * Bc + b);

  const _Float16* abase = Xt + (bb * Nc + n_w + lr) * Cc + lg * 8;
  const _Float16* bbase = Wh + ((size_t)br * Cc + o_w + lr) * Cc + lg * 8;
  f32x4 acc[4][4] = {};  // [ot][mt]

  for (int c0 = 0; c0 < Cc; c0 += 32) {
    f16x8 af[4], bfr[4];
#pragma unroll
    for (int mt = 0; mt < 4; ++mt)
      af[mt] = *(const f16x8*)(abase + (size_t)(mt * 16) * Cc + c0);
#pragma unroll
    for (int ot = 0; ot < 4; ++ot)
      bfr[ot] = *(const f16x8*)(bbase + (size_t)(ot * 16) * Cc + c0);
#pragma unroll
    for (int ot = 0; ot < 4; ++ot)
#pragma unroll
      for (int mt = 0; mt < 4; ++mt)
        acc[ot][mt] = __builtin_amdgcn_mfma_f32_16x16x32_f16(af[mt], bfr[ot], acc[ot][mt], 0, 0, 0);
  }
#pragma unroll
  for (int ot = 0; ot < 4; ++ot)
#pragma unroll
    for (int mt = 0; mt < 4; ++mt) {
      const int cout = o_w + ot * 16 + lr;
      const int n = n_w + mt * 16 + lg * 4;
      f16x4 o4;
#pragma unroll
      for (int r = 0; r < 4; ++r) o4[r] = (_Float16)acc[ot][mt][r];
      *(f16x4*)&Vb[(bb * Cc + cout) * Nc + n] = o4;
    }
}

// ---------------------------------------------------------------------------
// MFMA flash attention, wave-specialized, counted-vmcnt pipeline (T4):
// block = 768 threads (12 waves). Producers ws 0-3: K TRIPLE-buffered via
// global_load_lds; per-iter barrier is raw s_barrier with
// s_waitcnt vmcnt(2) lgkmcnt(0) (K(ch+2) stays IN FLIGHT across the barrier
// -- no vmcnt(0) drain). Consumers ws 4-11 (32-ch strip): V loads persist
// across the barrier (s_waitcnt lgkmcnt(0) only). Same parity scheme for
// p_lds/s_fac as r15. grid (Nc/64, nsp, 2*B).
// ---------------------------------------------------------------------------
__global__ __launch_bounds__(768, 3) void attn_mfma_kernel(
    const _Float16* __restrict__ Qt,   // [2B][N][64], pre-scaled by log2(e)
    const _Float16* __restrict__ Kt,   // [2B][N][64] pre-swizzled rows
    const _Float16* __restrict__ V,    // [2B][C][N]
    _Float16* __restrict__ Op,         // [2B][nsp][N][C] partial O
    float* __restrict__ Ml,            // [2B][nsp][N][2] (m, l in log2 domain)
    int nsp, int kn)
{
  __shared__ __align__(16) _Float16 k_lds[3][64 * 64];  // 3 x 8KB (triple buf)
  __shared__ __align__(16) _Float16 p_lds[2][64 * 64];  // 2 x 8KB
  __shared__ float s_fac[2][64];

  const int t  = threadIdx.x;
  const int ws = t >> 6;          // 0..11
  const int l  = t & 63;
  const int lr = l & 15;
  const int lg = l >> 4;

  const int nwg  = (Nc / 64) * nsp * 8;
  const int lin  = blockIdx.x + gridDim.x * (blockIdx.y + gridDim.y * blockIdx.z);
  const int work = (lin & 7) * (nwg >> 3) + (lin >> 3);
  const int m0   = (work & 63) * 64;
  const int spbb = work >> 6;
  const int sp   = spbb % nsp;
  const size_t bb = (size_t)(spbb / nsp);

  const _Float16* kgl = Kt + (bb * Nc + (size_t)sp * kn) * 64;
  const int nch = kn >> 6;   // 32 (nsp=2) or 64 (nsp=1), even

  if (ws < 4) {
    // ================= PRODUCER: QK + softmax =================
    const _Float16* qp = Qt + (bb * Nc + m0 + ws * 16 + lr) * 64 + lg * 8;
    const f16x8 qf0 = *(const f16x8*)qp;
    const f16x8 qf1 = *(const f16x8*)(qp + 32);
    const _Float16* gq = kgl + ws * 512 + l * 8;

    float m_run = -1e30f, l_run = 0.f;   // per-lane partial l
    const int mrow = ws * 16 + lr;
    const int sw   = (mrow & 7) << 4;

    {  // prologue: stage K(0)->buf0, K(1)->buf1; K(0) must land, K(1) flies
#pragma unroll
      for (int r = 0; r < 2; ++r)
        gload_lds16(gq + r * 2048, &k_lds[0][ws * 512 + r * 2048]);
#pragma unroll
      for (int r = 0; r < 2; ++r)
        gload_lds16(gq + (64 * 64) + r * 2048, &k_lds[1][ws * 512 + r * 2048]);
      asm volatile("s_waitcnt vmcnt(2)" ::: "memory");
    }
    __builtin_amdgcn_s_barrier();
    __builtin_amdgcn_sched_barrier(0);

    int cur = 0;   // k_lds buffer holding chunk ch
    for (int ch = 0; ch < nch; ++ch) {
      const int par = ch & 1;
      // stage K(ch+2) into buffer (cur+2)%3
      const bool more = (ch + 2 < nch);
      if (more) {
        int stg = cur + 2; if (stg >= 3) stg -= 3;
        const _Float16* g = gq + (size_t)(ch + 2) * (64 * 64);
#pragma unroll
        for (int r = 0; r < 2; ++r)
          gload_lds16(g + r * 2048, &k_lds[stg][ws * 512 + r * 2048]);
      }
      // QK^T for chunk ch from k_lds[cur]
      const _Float16* kbuf = &k_lds[cur][0];
      f32x4 st[4] = {};
#pragma unroll
      for (int nt = 0; nt < 4; ++nt) {
        const int   krow = nt * 16 + lr;
        const char* krp  = (const char*)(kbuf + krow * 64);
        const int   swr  = (krow & 7) << 4;
        f16x8 kh0 = *(const f16x8*)(krp + ((lg * 16) ^ swr));
        f16x8 kh1 = *(const f16x8*)(krp + ((64 + lg * 16) ^ swr));
        st[nt] = __builtin_amdgcn_mfma_f32_16x16x32_f16(kh0, qf0, st[nt], 0, 0, 0);
        st[nt] = __builtin_amdgcn_mfma_f32_16x16x32_f16(kh1, qf1, st[nt], 0, 0, 0);
      }
      // defer-max softmax (zero cross-lane steady state)
      float mx = st[0][0];
#pragma unroll
      for (int nt = 0; nt < 4; ++nt)
#pragma unroll
        for (int rr = 0; rr < 4; ++rr) mx = fmaxf(mx, st[nt][rr]);
      float s = 1.0f;
      if (__any(mx > m_run + 12.0f)) {
        mx = fmaxf(mx, __shfl_xor(mx, 16));
        mx = fmaxf(mx, __shfl_xor(mx, 32));
        const float mnew = fmaxf(m_run, mx);
        s = exp2fast(m_run - mnew);
        m_run = mnew;
      }
      float sum = 0.f;
      float p[4][4];
#pragma unroll
      for (int nt = 0; nt < 4; ++nt)
#pragma unroll
        for (int rr = 0; rr < 4; ++rr) {
          p[nt][rr] = exp2fast(st[nt][rr] - m_run);
          sum += p[nt][rr];
        }
      l_run = l_run * s + sum;
      {
        char* prow = (char*)&p_lds[par][mrow * 64];
#pragma unroll
        for (int nt = 0; nt < 4; ++nt) {
          f16x4 pb;
          pb[0] = (_Float16)p[nt][0]; pb[1] = (_Float16)p[nt][1];
          pb[2] = (_Float16)p[nt][2]; pb[3] = (_Float16)p[nt][3];
          *(f16x4*)(prow + ((nt * 32 + lg * 8) ^ sw)) = pb;
        }
      }
      if (lg == 0) s_fac[par][ws * 16 + lr] = s;
      // counted-vmcnt barrier: K(ch+1) done, K(ch+2) stays in flight
      if (more) {
        asm volatile("s_waitcnt vmcnt(2) lgkmcnt(0)" ::: "memory");
      } else {
        asm volatile("s_waitcnt vmcnt(0) lgkmcnt(0)" ::: "memory");
      }
      __builtin_amdgcn_s_barrier();
      __builtin_amdgcn_sched_barrier(0);
      cur = (cur + 1 == 3) ? 0 : cur + 1;
    }

    // epilogue: reduce per-lane partial l, write stats
    l_run += __shfl_xor(l_run, 16);
    l_run += __shfl_xor(l_run, 32);
    if (lg == 0) {
      size_t mi = ((bb * nsp + sp) * Nc + m0 + ws * 16 + lr) * 2;
      Ml[mi]     = m_run;
      Ml[mi + 1] = l_run;
    }
  } else {
    // ================= CONSUMER: PV (32-channel strip per wave) ============
    const int cw = ws - 4;   // 0..7
    const _Float16* vbase = V + (bb * Cc + cw * 32 + lr) * Nc + sp * kn + lg * 8;
    f32x4 acc[2][4] = {};
    f16x8 vf[2][2][2];   // [parity][ct][kk]

    __builtin_amdgcn_s_barrier();   // match producer prologue barrier
    __builtin_amdgcn_sched_barrier(0);

    for (int ch2 = 0; ch2 < nch; ch2 += 2) {
#pragma unroll
      for (int par = 0; par < 2; ++par) {
        const int ch = ch2 + par;
        // V prefetch for chunk ch (consumed next sub-iter; stays in flight
        // across the raw s_barrier -- no vmcnt drain on this path)
        {
          const _Float16* vp = vbase + ch * 64;
#pragma unroll
          for (int ct = 0; ct < 2; ++ct)
#pragma unroll
            for (int kk = 0; kk < 2; ++kk)
              vf[par][ct][kk] = *(const f16x8*)(vp + (size_t)ct * 16 * Nc + kk * 32);
        }
        // PV for chunk ch-1 (p_lds/s_fac from par^1; vf[par^1])
        if (ch > 0) {
          float scm[4];
#pragma unroll
          for (int mt = 0; mt < 4; ++mt) scm[mt] = s_fac[par ^ 1][mt * 16 + lr];
          const int needs = (scm[0] != 1.f) | (scm[1] != 1.f) |
                            (scm[2] != 1.f) | (scm[3] != 1.f);
          if (__any(needs)) {
#pragma unroll
            for (int ct = 0; ct < 2; ++ct)
#pragma unroll
              for (int mt = 0; mt < 4; ++mt) {
                acc[ct][mt][0] *= scm[mt]; acc[ct][mt][1] *= scm[mt];
                acc[ct][mt][2] *= scm[mt]; acc[ct][mt][3] *= scm[mt];
              }
          }
          f16x8 pf[4][2];
#pragma unroll
          for (int mt = 0; mt < 4; ++mt) {
            const int   rm  = mt * 16 + lr;
            const char* pr  = (const char*)&p_lds[par ^ 1][rm * 64];
            const int   swr = (rm & 7) << 4;
#pragma unroll
            for (int kk = 0; kk < 2; ++kk)
              pf[mt][kk] = *(const f16x8*)(pr + ((lg * 16 + kk * 64) ^ swr));
          }
          __builtin_amdgcn_s_setprio(1);
#pragma unroll
          for (int ct = 0; ct < 2; ++ct)
#pragma unroll
            for (int kk = 0; kk < 2; ++kk)
#pragma unroll
              for (int mt = 0; mt < 4; ++mt)
                acc[ct][mt] = __builtin_amdgcn_mfma_f32_16x16x32_f16(vf[par ^ 1][ct][kk], pf[mt][kk], acc[ct][mt], 0, 0, 0);
          __builtin_amdgcn_s_setprio(0);
        }
        asm volatile("s_waitcnt lgkmcnt(0)" ::: "memory");
        __builtin_amdgcn_s_barrier();
        __builtin_amdgcn_sched_barrier(0);
      }
    }

    // epilogue PV (last chunk: parity 1, nch even)
    {
      float scm[4];
#pragma unroll
      for (int mt = 0; mt < 4; ++mt) scm[mt] = s_fac[1][mt * 16 + lr];
      const int needs = (scm[0] != 1.f) | (scm[1] != 1.f) |
                        (scm[2] != 1.f) | (scm[3] != 1.f);
      if (__any(needs)) {
#pragma unroll
        for (int ct = 0; ct < 2; ++ct)
#pragma unroll
          for (int mt = 0; mt < 4; ++mt) {
            acc[ct][mt][0] *= scm[mt]; acc[ct][mt][1] *= scm[mt];
            acc[ct][mt][2] *= scm[mt]; acc[ct][mt][3] *= scm[mt];
          }
      }
      f16x8 pf[4][2];
#pragma unroll
      for (int mt = 0; mt < 4; ++mt) {
        const int   rm  = mt * 16 + lr;
        const char* pr  = (const char*)&p_lds[1][rm * 64];
        const int   swr = (rm & 7) << 4;
#pragma unroll
        for (int kk = 0; kk < 2; ++kk)
          pf[mt][kk] = *(const f16x8*)(pr + ((lg * 16 + kk * 64) ^ swr));
      }
#pragma unroll
      for (int ct = 0; ct < 2; ++ct)
#pragma unroll
        for (int kk = 0; kk < 2; ++kk)
#pragma unroll
          for (int mt = 0; mt < 4; ++mt)
            acc[ct][mt] = __builtin_amdgcn_mfma_f32_16x16x32_f16(vf[1][ct][kk], pf[mt][kk], acc[ct][mt], 0, 0, 0);
    }

    // write unnormalized partial O as [m][c] (c-contiguous)
    _Float16* ob = Op + (bb * nsp + sp) * (size_t)Cc * Nc;
#pragma unroll
    for (int ct = 0; ct < 2; ++ct)
#pragma unroll
      for (int mt = 0; mt < 4; ++mt) {
        const int c0 = cw * 32 + ct * 16 + lg * 4;
        const int m  = m0 + mt * 16 + lr;
        f16x4 o4;
#pragma unroll
        for (int r = 0; r < 4; ++r) o4[r] = (_Float16)acc[ct][mt][r];
        *(f16x4*)&ob[(size_t)m * Cc + c0] = o4;
      }
  }
}

// ---------------------------------------------------------------------------
// Combine partials -> normalized r, fp16 [2B][m][c]. m,l are log2-domain.
// ---------------------------------------------------------------------------
__global__ __launch_bounds__(256) void combine_kernel(
    const _Float16* __restrict__ Op, const float* __restrict__ Ml,
    _Float16* __restrict__ Rt, int nsp)
{
  const int tid = blockIdx.x * 256 + threadIdx.x;
  const int c0 = (tid & 63) * 4;
  const int m  = (tid >> 6) & (Nc - 1);
  const int bb = tid >> 18;
  float val[4];
  if (nsp == 2) {
    const _Float16* o0 = Op + ((size_t)bb * 2 + 0) * Cc * Nc + (size_t)m * Cc + c0;
    const _Float16* o1 = Op + ((size_t)bb * 2 + 1) * Cc * Nc + (size_t)m * Cc + c0;
    const float* ml0 = Ml + (((size_t)bb * 2 + 0) * Nc + m) * 2;
    const float* ml1 = Ml + (((size_t)bb * 2 + 1) * Nc + m) * 2;
    float m1 = ml0[0], L1 = ml0[1], m2 = ml1[0], L2 = ml1[1];
    float M  = fmaxf(m1, m2);
    float w1 = __builtin_amdgcn_exp2f(m1 - M), w2 = __builtin_amdgcn_exp2f(m2 - M);
    float inv = 1.0f / (w1 * L1 + w2 * L2);
    f16x4 a = *(const f16x4*)o0;
    f16x4 d = *(const f16x4*)o1;
#pragma unroll
    for (int j = 0; j < 4; ++j) val[j] = (w1 * (float)a[j] + w2 * (float)d[j]) * inv;
  } else {
    const _Float16* o0 = Op + (size_t)bb * Cc * Nc + (size_t)m * Cc + c0;
    const float* ml0 = Ml + ((size_t)bb * Nc + m) * 2;
    float inv = 1.0f / ml0[1];
    f16x4 a = *(const f16x4*)o0;
#pragma unroll
    for (int j = 0; j < 4; ++j) val[j] = (float)a[j] * inv;
  }
  f16x4 r4;
#pragma unroll
  for (int j = 0; j < 4; ++j) r4[j] = (_Float16)val[j];
  *(f16x4*)&Rt[((size_t)bb * Nc + m) * Cc + c0] = r4;
}

// ---------------------------------------------------------------------------
// t = w_t @ r via MFMA -> Th fp16 [2B][o][m], plus per-block BN partial sums
// (partials from exact fp32 accumulators). grid (Nc/128, Cc/128, 8)
// ---------------------------------------------------------------------------
__global__ __launch_bounds__(256, 4) void conv_t_mfma_kernel(
    const _Float16* __restrict__ Rt, const _Float16* __restrict__ Wh,
    _Float16* __restrict__ Th, float* __restrict__ part)
{
  __shared__ float red[2][2][4][16][2];
  const int t  = threadIdx.x;
  const int ws = t >> 6, l = t & 63, lr = l & 15, lg = l >> 4;
  const int wm = ws >> 1, wo = ws & 1;
  const int m_w = blockIdx.x * 128 + wm * 64;
  const int o_w = blockIdx.y * 128 + wo * 64;
  const int z  = blockIdx.z, br = z >> 2, b = z & 3;
  const size_t bb = (size_t)(br * Bc + b);

  const _Float16* abase = Rt + (bb * Nc + m_w + lr) * Cc + lg * 8;
  const _Float16* bbase = Wh + ((size_t)(2 + br) * Cc + o_w + lr) * Cc + lg * 8;
  f32x4 acc[4][4] = {};  // [ot][mt]

  for (int c0 = 0; c0 < Cc; c0 += 32) {
    f16x8 af[4], bfr[4];
#pragma unroll
    for (int mt = 0; mt < 4; ++mt)
      af[mt] = *(const f16x8*)(abase + (size_t)(mt * 16) * Cc + c0);
#pragma unroll
    for (int ot = 0; ot < 4; ++ot)
      bfr[ot] = *(const f16x8*)(bbase + (size_t)(ot * 16) * Cc + c0);
#pragma unroll
    for (int ot = 0; ot < 4; ++ot)
#pragma unroll
      for (int mt = 0; mt < 4; ++mt)
        acc[ot][mt] = __builtin_amdgcn_mfma_f32_16x16x32_f16(af[mt], bfr[ot], acc[ot][mt], 0, 0, 0);
  }
  _Float16* Tb = Th + bb * Cc * Nc;
#pragma unroll
  for (int ot = 0; ot < 4; ++ot) {
    float s = 0.f, q = 0.f;
#pragma unroll
    for (int mt = 0; mt < 4; ++mt) {
      const int o = o_w + ot * 16 + lr;
      const int m = m_w + mt * 16 + lg * 4;
      f16x4 h4;
#pragma unroll
      for (int r = 0; r < 4; ++r) {
        float v = acc[ot][mt][r];
        h4[r] = (_Float16)v;
        s += v; q += v * v;
      }
      *(f16x4*)&Tb[(size_t)o * Nc + m] = h4;
    }
    s += __shfl_xor(s, 16); s += __shfl_xor(s, 32);
    q += __shfl_xor(q, 16); q += __shfl_xor(q, 32);
    if (lg == 0) { red[wm][wo][ot][lr][0] = s; red[wm][wo][ot][lr][1] = q; }
  }
  __syncthreads();
  {
    const int wo2 = t >> 7, ot2 = (t >> 5) & 3, lr2 = (t >> 1) & 15, kind = t & 1;
    float v = red[0][wo2][ot2][lr2][kind] + red[1][wo2][ot2][lr2][kind];
    const int c = blockIdx.y * 128 + wo2 * 64 + ot2 * 16 + lr2;
    const int slot = blockIdx.x * 4 + b;
    part[(((size_t)br * Cc + c) * 128 + slot) * 2 + kind] = v;
  }
}

// ---------------------------------------------------------------------------
// finalize BN stats: mean / istd per (br, channel)
// ---------------------------------------------------------------------------
__global__ __launch_bounds__(256) void bn_finalize_kernel(
    const float* __restrict__ part, float* __restrict__ stats)
{
  const int br = blockIdx.x, c = threadIdx.x;
  const float* p = part + ((size_t)br * Cc + c) * 128 * 2;
  float s = 0.f, q = 0.f;
#pragma unroll 4
  for (int i = 0; i < 128; ++i) { s += p[i * 2]; q += p[i * 2 + 1]; }
  const float inv_n = 1.0f / (float)(Bc * Nc);
  const float mean = s * inv_n;
  const float var  = q * inv_n - mean * mean;
  stats[(br * 2 + 0) * Cc + c] = mean;
  stats[(br * 2 + 1) * Cc + c] = rsqrtf(var + 1e-5f);
}

// ---------------------------------------------------------------------------
// Epilogue: OUT = SRC + relu(bn(Th)) -> d_out (fp32)
// ---------------------------------------------------------------------------
__global__ __launch_bounds__(256) void bn_out_kernel(
    const _Float16* __restrict__ Th, float* __restrict__ OUT,
    const float* __restrict__ X, const float* __restrict__ Y,
    const float* __restrict__ stats, const float* __restrict__ gamma,
    const float* __restrict__ beta)
{
  const int br = blockIdx.y;
  const int i = blockIdx.x * 256 + threadIdx.x;
  const size_t flat = ((size_t)i << 2);
  const int c = (int)((flat >> 12) & (Cc - 1));
  float mean = stats[(br * 2 + 0) * Cc + c], istd = stats[(br * 2 + 1) * Cc + c];
  float gm = gamma[c], bt = beta[c];
  const _Float16* Tb = Th + (size_t)br * Bc * Cc * Nc;
  float* Ob = OUT + (size_t)br * Bc * Cc * Nc;
  const float* SRC = (br ? Y : X);
  f16x4 t4 = *(const f16x4*)&Tb[flat];
  float4 s4 = *(const float4*)&SRC[flat];
  float4 o4;
  o4.x = s4.x + fmaxf(0.f, gm * ((float)t4[0] - mean) * istd + bt);
  o4.y = s4.y + fmaxf(0.f, gm * ((float)t4[1] - mean) * istd + bt);
  o4.z = s4.z + fmaxf(0.f, gm * ((float)t4[2] - mean) * istd + bt);
  o4.w = s4.w + fmaxf(0.f, gm * ((float)t4[3] - mean) * istd + bt);
  *(float4*)&Ob[flat] = o4;
}

// ---------------------------------------------------------------------------
extern "C" void kernel_launch(void* const* d_in, const int* in_sizes, int n_in,
                              void* d_out, int out_size, void* d_ws, size_t ws_size,
                              hipStream_t stream) {
  const float* x     = (const float*)d_in[0];
  const float* y     = (const float*)d_in[1];
  const float* w_qkx = (const float*)d_in[2];
  const float* w_vx  = (const float*)d_in[3];
  const float* w_tx  = (const float*)d_in[4];
  const float* w_qky = (const float*)d_in[5];
  const float* w_vy  = (const float*)d_in[6];
  const float* w_ty  = (const float*)d_in[7];
  const float* gamma = (const float*)d_in[8];
  const float* beta  = (const float*)d_in[9];

  float* out = (float*)d_out;  // [2][B][C][N]

  const int nsp = (ws_size >= 60ull * 1024 * 1024) ? 2 : 1;
  const int kn  = Nc / nsp;

  char* wsb = (char*)d_ws;
  _Float16* qt = (_Float16*)wsb;                        // 4 MB [2B][N][64]
  _Float16* kt = (_Float16*)(wsb + (4ull << 20));       // 4 MB (pre-swizzled)
  _Float16* vb = (_Float16*)(wsb + (8ull << 20));       // 16 MB [2B][C][N]
  _Float16* xt = (_Float16*)(wsb + (24ull << 20));      // 16 MB [2][B][N][C]
  _Float16* op = (_Float16*)(wsb + (24ull << 20));      // nsp*16 MB (overlays xt)
  size_t off = (24ull << 20) + (size_t)nsp * (16ull << 20);
  float* ml = (float*)(wsb + off);                      // nsp*256 KB
  off += (size_t)nsp * (256ull << 10);
  _Float16* wh = (_Float16*)(wsb + off);                // 576 KB weights fp16
  off += (640ull << 10);
  float* part = (float*)(wsb + off);                    // 512 KB partial sums
  off += (512ull << 10);
  float* st = (float*)(wsb + off);                      // 8 KB stats
  _Float16* rt = (_Float16*)wsb;                        // 16 MB, overlays qt/kt/vb-head
  _Float16* th = (_Float16*)(wsb + (24ull << 20));      // 17 MB, overlays op (dead after combine)

  wconv_kernel<<<dim3(Cc * Cc / 256, 6), 256, 0, stream>>>(w_vx, w_vy, w_tx, w_ty, w_qkx, w_qky, wh);
  transpose_kernel<<<dim3(Nc / 64, Cc / 64, 8), 256, 0, stream>>>(x, y, xt);
  conv_qk_mfma_kernel<<<dim3(Nc / 128, 2, 8), 256, 0, stream>>>(xt, wh, qt, kt);
  conv_v_mfma_kernel<<<dim3(Nc / 128, Cc / 128, 8), 256, 0, stream>>>(xt, wh, vb);
  attn_mfma_kernel<<<dim3(Nc / 64, nsp, 8), 768, 0, stream>>>(qt, kt, vb, op, ml, nsp, kn);
  combine_kernel<<<(2 * Bc * Nc * (Cc / 4)) / 256, 256, 0, stream>>>(op, ml, rt, nsp);
  conv_t_mfma_kernel<<<dim3(Nc / 128, Cc / 128, 8), 256, 0, stream>>>(rt, wh, th, part);
  bn_finalize_kernel<<<2, 256, 0, stream>>>(part, st);
  bn_out_kernel<<<dim3((Bc * Cc * Nc / 4) / 256, 2), 256, 0, stream>>>(th, out, x, y, st, gamma, beta);
}

// Round 19
// 230.434 us; speedup vs baseline: 1.2801x; 1.1578x over previous
//
#include <hip/hip_runtime.h>

constexpr int Bc = 4;     // batch
constexpr int Cc = 256;   // channels
constexpr int Dc = 64;    // q/k dim
constexpr int Nc = 4096;  // sequence length

typedef __attribute__((ext_vector_type(8))) _Float16 f16x8;
typedef __attribute__((ext_vector_type(4))) _Float16 f16x4;
typedef __attribute__((ext_vector_type(4))) float f32x4;

__device__ inline float exp2fast(float x) { return __builtin_amdgcn_exp2f(x); }

// async 16B global->LDS (wave-uniform LDS base, per-lane global addr)
__device__ inline void gload_lds16(const _Float16* g, _Float16* lds) {
  __builtin_amdgcn_global_load_lds(
      (const __attribute__((address_space(1))) unsigned int*)g,
      (__attribute__((address_space(3))) unsigned int*)lds, 16, 0, 0);
}

// ---------------------------------------------------------------------------
// weights -> fp16. z: 0..3 = {w_vx,w_vy,w_tx,w_ty} (C*C), 4..5 = {w_qkx,w_qky}
// ---------------------------------------------------------------------------
__global__ __launch_bounds__(256) void wconv_kernel(
    const float* __restrict__ Wvx, const float* __restrict__ Wvy,
    const float* __restrict__ Wtx, const float* __restrict__ Wty,
    const float* __restrict__ Wqkx, const float* __restrict__ Wqky,
    _Float16* __restrict__ Wh)
{
  const int i = blockIdx.x * 256 + threadIdx.x;
  const int z = blockIdx.y;
  if (z < 4) {
    const float* w = (z == 0) ? Wvx : (z == 1) ? Wvy : (z == 2) ? Wtx : Wty;
    Wh[(size_t)z * Cc * Cc + i] = (_Float16)w[i];
  } else if (i < Dc * Cc) {
    const float* w = (z == 4) ? Wqkx : Wqky;
    Wh[(size_t)4 * Cc * Cc + (size_t)(z - 4) * Dc * Cc + i] = (_Float16)w[i];
  }
}

// ---------------------------------------------------------------------------
// transpose-cast: x,y fp32 [b][c][n] -> Xt fp16 [src][b][n][c]
// grid (Nc/64, Cc/64, 8 {src,b})
// ---------------------------------------------------------------------------
__global__ __launch_bounds__(256) void transpose_kernel(
    const float* __restrict__ X, const float* __restrict__ Y,
    _Float16* __restrict__ Xt)
{
  __shared__ float tile[64][65];
  const int t  = threadIdx.x;
  const int n0 = blockIdx.x * 64;
  const int c0 = blockIdx.y * 64;
  const int z  = blockIdx.z, br = z >> 2, b = z & 3;
  const float* In = (br ? Y : X) + (size_t)b * Cc * Nc;
#pragma unroll
  for (int p = 0; p < 4; ++p) {
    const int c = p * 16 + (t >> 4), n4 = (t & 15) * 4;
    float4 v = *(const float4*)&In[(size_t)(c0 + c) * Nc + n0 + n4];
    tile[c][n4 + 0] = v.x; tile[c][n4 + 1] = v.y;
    tile[c][n4 + 2] = v.z; tile[c][n4 + 3] = v.w;
  }
  __syncthreads();
  _Float16* Ob = Xt + ((size_t)(br * Bc + b) * Nc + n0) * Cc + c0;
#pragma unroll
  for (int p = 0; p < 4; ++p) {
    const int n = p * 16 + (t >> 4), c4 = (t & 15) * 4;
    f16x4 w;
#pragma unroll
    for (int j = 0; j < 4; ++j) w[j] = (_Float16)tile[c4 + j][n];
    *(f16x4*)&Ob[(size_t)n * Cc + c4] = w;
  }
}

// ---------------------------------------------------------------------------
// q/k conv via MFMA: Out[n][d] = sum_c Wqk[d][c] * Xt[n][c]
// Q is scaled by log2(e) so attention softmax can use exp2 directly.
// K rows PRE-SWIZZLED (half-off ^= (n&7)<<3). grid (Nc/128, 2 {q,k}, 8)
// ---------------------------------------------------------------------------
__global__ __launch_bounds__(256, 4) void conv_qk_mfma_kernel(
    const _Float16* __restrict__ Xt, const _Float16* __restrict__ Wh,
    _Float16* __restrict__ Qt, _Float16* __restrict__ Kt)
{
  const int t  = threadIdx.x;
  const int ws = t >> 6, l = t & 63, lr = l & 15, lg = l >> 4;
  const int n_w = blockIdx.x * 128 + ws * 32;
  const int qk = blockIdx.y;
  const int z  = blockIdx.z, br = z >> 2, b = z & 3;
  const size_t bb = (size_t)(br * Bc + b);
  const int insel = (qk ^ br ^ 1) & 1;   // 0=x, 1=y
  _Float16* Out = qk ? Kt : Qt;
  const float scale = qk ? 1.0f : 1.44269504088896f;

  const _Float16* wbase = Wh + (size_t)4 * Cc * Cc + (size_t)br * Dc * Cc
                          + (size_t)lr * Cc + lg * 8;
  const _Float16* xbase = Xt + ((size_t)(insel * Bc + b) * Nc + n_w + lr) * Cc + lg * 8;

  f32x4 acc[4][2] = {};  // [dt][nt]
  for (int c0 = 0; c0 < Cc; c0 += 32) {
    f16x8 wf[4], xf[2];
#pragma unroll
    for (int dt = 0; dt < 4; ++dt)
      wf[dt] = *(const f16x8*)(wbase + (size_t)(dt * 16) * Cc + c0);
#pragma unroll
    for (int nt = 0; nt < 2; ++nt)
      xf[nt] = *(const f16x8*)(xbase + (size_t)(nt * 16) * Cc + c0);
#pragma unroll
    for (int dt = 0; dt < 4; ++dt)
#pragma unroll
      for (int nt = 0; nt < 2; ++nt)
        acc[dt][nt] = __builtin_amdgcn_mfma_f32_16x16x32_f16(wf[dt], xf[nt], acc[dt][nt], 0, 0, 0);
  }
#pragma unroll
  for (int dt = 0; dt < 4; ++dt)
#pragma unroll
    for (int nt = 0; nt < 2; ++nt) {
      const int n  = n_w + nt * 16 + lr;
      const int d0 = dt * 16 + lg * 4;
      const int off = qk ? (d0 ^ ((n & 7) << 3)) : d0;
      f16x4 o4;
#pragma unroll
      for (int r = 0; r < 4; ++r) o4[r] = (_Float16)(acc[dt][nt][r] * scale);
      *(f16x4*)&Out[(bb * Nc + n) * 64 + off] = o4;
    }
}

// ---------------------------------------------------------------------------
// v conv via MFMA: V[cout][n] = sum_c Wv[cout][c] * Xt[n][c]
// grid (Nc/128, Cc/128, 8), block 256 (2x2 wave grid)
// ---------------------------------------------------------------------------
__global__ __launch_bounds__(256, 4) void conv_v_mfma_kernel(
    const _Float16* __restrict__ Xt, const _Float16* __restrict__ Wh,
    _Float16* __restrict__ Vb)
{
  const int t  = threadIdx.x;
  const int ws = t >> 6, l = t & 63, lr = l & 15, lg = l >> 4;
  const int wm = ws >> 1, wo = ws & 1;
  const int n_w = blockIdx.x * 128 + wm * 64;
  const int o_w = blockIdx.y * 128 + wo * 64;
  const int z  = blockIdx.z, br = z >> 2, b = z & 3;
  const size_t bb = (size_t)(br * Bc + b);

  const _Float16* abase = Xt + (bb * Nc + n_w + lr) * Cc + lg * 8;
  const _Float16* bbase = Wh + ((size_t)br * Cc + o_w + lr) * Cc + lg * 8;
  f32x4 acc[4][4] = {};  // [ot][mt]

  for (int c0 = 0; c0 < Cc; c0 += 32) {
    f16x8 af[4], bfr[4];
#pragma unroll
    for (int mt = 0; mt < 4; ++mt)
      af[mt] = *(const f16x8*)(abase + (size_t)(mt * 16) * Cc + c0);
#pragma unroll
    for (int ot = 0; ot < 4; ++ot)
      bfr[ot] = *(const f16x8*)(bbase + (size_t)(ot * 16) * Cc + c0);
#pragma unroll
    for (int ot = 0; ot < 4; ++ot)
#pragma unroll
      for (int mt = 0; mt < 4; ++mt)
        acc[ot][mt] = __builtin_amdgcn_mfma_f32_16x16x32_f16(af[mt], bfr[ot], acc[ot][mt], 0, 0, 0);
  }
#pragma unroll
  for (int ot = 0; ot < 4; ++ot)
#pragma unroll
    for (int mt = 0; mt < 4; ++mt) {
      const int cout = o_w + ot * 16 + lr;
      const int n = n_w + mt * 16 + lg * 4;
      f16x4 o4;
#pragma unroll
      for (int r = 0; r < 4; ++r) o4[r] = (_Float16)acc[ot][mt][r];
      *(f16x4*)&Vb[(bb * Cc + cout) * Nc + n] = o4;
    }
}

// ---------------------------------------------------------------------------
// MFMA flash attention, wave-specialized (r15 structure), NO KV-split:
// each block covers the full key range, so the consumer can NORMALIZE
// in-kernel (producer hands final l via s_fac[0] + one matched barrier)
// and write rt fp16 [2B][m][c] directly -- no partial-O buffer, no combine.
// block = 768 threads: producers ws 0-3 (K staging dbuf + QK + defer-max
// softmax + P/s_fac), consumers ws 4-11 (32-ch strip, V parity prefetch +
// PV). grid (Nc/64, 1, 8).
// ---------------------------------------------------------------------------
__global__ __launch_bounds__(768, 3) void attn_mfma_kernel(
    const _Float16* __restrict__ Qt,   // [2B][N][64], pre-scaled by log2(e)
    const _Float16* __restrict__ Kt,   // [2B][N][64] pre-swizzled rows
    const _Float16* __restrict__ V,    // [2B][C][N]
    _Float16* __restrict__ Rt)         // [2B][N][C] normalized output
{
  __shared__ __align__(16) _Float16 k_lds[2][64 * 64];  // 2 x 8KB
  __shared__ __align__(16) _Float16 p_lds[2][64 * 64];  // 2 x 8KB
  __shared__ float s_fac[2][64];       // s_fac[0] doubles as final-l channel

  const int t  = threadIdx.x;
  const int ws = t >> 6;          // 0..11
  const int l  = t & 63;
  const int lr = l & 15;
  const int lg = l >> 4;

  // XCD-aware bijective remap (nwg = 512, divisible by 8)
  const int nwg  = (Nc / 64) * 8;
  const int lin  = blockIdx.x + gridDim.x * blockIdx.z;
  const int work = (lin & 7) * (nwg >> 3) + (lin >> 3);
  const int m0   = (work & 63) * 64;
  const size_t bb = (size_t)(work >> 6);

  const _Float16* kgl = Kt + bb * Nc * 64;
  const int nch = Nc >> 6;   // 64 chunks, even

  if (ws < 4) {
    // ================= PRODUCER: QK + softmax =================
    const _Float16* qp = Qt + (bb * Nc + m0 + ws * 16 + lr) * 64 + lg * 8;
    const f16x8 qf0 = *(const f16x8*)qp;
    const f16x8 qf1 = *(const f16x8*)(qp + 32);
    const _Float16* gq = kgl + ws * 512 + l * 8;

    float m_run = -1e30f, l_run = 0.f;   // per-lane partial l
    const int mrow = ws * 16 + lr;
    const int sw   = (mrow & 7) << 4;

    {  // prologue: chunk 0 -> k_lds[0]
#pragma unroll
      for (int r = 0; r < 2; ++r)
        gload_lds16(gq + r * 2048, &k_lds[0][ws * 512 + r * 2048]);
    }
    __syncthreads();

    for (int ch2 = 0; ch2 < nch; ch2 += 2) {
#pragma unroll
      for (int par = 0; par < 2; ++par) {
        const int ch = ch2 + par;
        // stage K(ch+1) into k_lds[par^1]
        if (ch + 1 < nch) {
          const _Float16* g = gq + (size_t)(ch + 1) * (64 * 64);
#pragma unroll
          for (int r = 0; r < 2; ++r)
            gload_lds16(g + r * 2048, &k_lds[par ^ 1][ws * 512 + r * 2048]);
        }
        // QK^T for chunk ch from k_lds[par]
        f32x4 st[4] = {};
#pragma unroll
        for (int nt = 0; nt < 4; ++nt) {
          const int   krow = nt * 16 + lr;
          const char* krp  = (const char*)&k_lds[par][krow * 64];
          const int   swr  = (krow & 7) << 4;
          f16x8 kh0 = *(const f16x8*)(krp + ((lg * 16) ^ swr));
          f16x8 kh1 = *(const f16x8*)(krp + ((64 + lg * 16) ^ swr));
          st[nt] = __builtin_amdgcn_mfma_f32_16x16x32_f16(kh0, qf0, st[nt], 0, 0, 0);
          st[nt] = __builtin_amdgcn_mfma_f32_16x16x32_f16(kh1, qf1, st[nt], 0, 0, 0);
        }
        // defer-max softmax (zero cross-lane steady state)
        float mx = st[0][0];
#pragma unroll
        for (int nt = 0; nt < 4; ++nt)
#pragma unroll
          for (int rr = 0; rr < 4; ++rr) mx = fmaxf(mx, st[nt][rr]);
        float s = 1.0f;
        if (__any(mx > m_run + 12.0f)) {
          mx = fmaxf(mx, __shfl_xor(mx, 16));
          mx = fmaxf(mx, __shfl_xor(mx, 32));
          const float mnew = fmaxf(m_run, mx);
          s = exp2fast(m_run - mnew);
          m_run = mnew;
        }
        float sum = 0.f;
        float p[4][4];
#pragma unroll
        for (int nt = 0; nt < 4; ++nt)
#pragma unroll
          for (int rr = 0; rr < 4; ++rr) {
            p[nt][rr] = exp2fast(st[nt][rr] - m_run);
            sum += p[nt][rr];
          }
        l_run = l_run * s + sum;
        {
          char* prow = (char*)&p_lds[par][mrow * 64];
#pragma unroll
          for (int nt = 0; nt < 4; ++nt) {
            f16x4 pb;
            pb[0] = (_Float16)p[nt][0]; pb[1] = (_Float16)p[nt][1];
            pb[2] = (_Float16)p[nt][2]; pb[3] = (_Float16)p[nt][3];
            *(f16x4*)(prow + ((nt * 32 + lg * 8) ^ sw)) = pb;
          }
        }
        if (lg == 0) s_fac[par][ws * 16 + lr] = s;
        __syncthreads();
      }
    }

    // epilogue: reduce per-lane partial l, hand final l to consumers
    l_run += __shfl_xor(l_run, 16);
    l_run += __shfl_xor(l_run, 32);
    if (lg == 0) s_fac[0][mrow] = l_run;
    __syncthreads();   // matched by consumer's final barrier
  } else {
    // ================= CONSUMER: PV (32-channel strip per wave) ============
    const int cw = ws - 4;   // 0..7
    const _Float16* vbase = V + (bb * Cc + cw * 32 + lr) * Nc + lg * 8;
    f32x4 acc[2][4] = {};
    f16x8 vf[2][2][2];   // [parity][ct][kk]

    __syncthreads();   // match producer prologue barrier

    for (int ch2 = 0; ch2 < nch; ch2 += 2) {
#pragma unroll
      for (int par = 0; par < 2; ++par) {
        const int ch = ch2 + par;
        // V prefetch for chunk ch (consumed next sub-iter)
        {
          const _Float16* vp = vbase + ch * 64;
#pragma unroll
          for (int ct = 0; ct < 2; ++ct)
#pragma unroll
            for (int kk = 0; kk < 2; ++kk)
              vf[par][ct][kk] = *(const f16x8*)(vp + (size_t)ct * 16 * Nc + kk * 32);
        }
        // PV for chunk ch-1 (p_lds/s_fac from par^1; vf[par^1])
        if (ch > 0) {
          float scm[4];
#pragma unroll
          for (int mt = 0; mt < 4; ++mt) scm[mt] = s_fac[par ^ 1][mt * 16 + lr];
          const int needs = (scm[0] != 1.f) | (scm[1] != 1.f) |
                            (scm[2] != 1.f) | (scm[3] != 1.f);
          if (__any(needs)) {
#pragma unroll
            for (int ct = 0; ct < 2; ++ct)
#pragma unroll
              for (int mt = 0; mt < 4; ++mt) {
                acc[ct][mt][0] *= scm[mt]; acc[ct][mt][1] *= scm[mt];
                acc[ct][mt][2] *= scm[mt]; acc[ct][mt][3] *= scm[mt];
              }
          }
          f16x8 pf[4][2];
#pragma unroll
          for (int mt = 0; mt < 4; ++mt) {
            const int   rm  = mt * 16 + lr;
            const char* pr  = (const char*)&p_lds[par ^ 1][rm * 64];
            const int   swr = (rm & 7) << 4;
#pragma unroll
            for (int kk = 0; kk < 2; ++kk)
              pf[mt][kk] = *(const f16x8*)(pr + ((lg * 16 + kk * 64) ^ swr));
          }
          __builtin_amdgcn_s_setprio(1);
#pragma unroll
          for (int ct = 0; ct < 2; ++ct)
#pragma unroll
            for (int kk = 0; kk < 2; ++kk)
#pragma unroll
              for (int mt = 0; mt < 4; ++mt)
                acc[ct][mt] = __builtin_amdgcn_mfma_f32_16x16x32_f16(vf[par ^ 1][ct][kk], pf[mt][kk], acc[ct][mt], 0, 0, 0);
          __builtin_amdgcn_s_setprio(0);
        }
        __syncthreads();
      }
    }

    // epilogue PV (last chunk: parity 1, nch even)
    {
      float scm[4];
#pragma unroll
      for (int mt = 0; mt < 4; ++mt) scm[mt] = s_fac[1][mt * 16 + lr];
      const int needs = (scm[0] != 1.f) | (scm[1] != 1.f) |
                        (scm[2] != 1.f) | (scm[3] != 1.f);
      if (__any(needs)) {
#pragma unroll
        for (int ct = 0; ct < 2; ++ct)
#pragma unroll
          for (int mt = 0; mt < 4; ++mt) {
            acc[ct][mt][0] *= scm[mt]; acc[ct][mt][1] *= scm[mt];
            acc[ct][mt][2] *= scm[mt]; acc[ct][mt][3] *= scm[mt];
          }
      }
      f16x8 pf[4][2];
#pragma unroll
      for (int mt = 0; mt < 4; ++mt) {
        const int   rm  = mt * 16 + lr;
        const char* pr  = (const char*)&p_lds[1][rm * 64];
        const int   swr = (rm & 7) << 4;
#pragma unroll
        for (int kk = 0; kk < 2; ++kk)
          pf[mt][kk] = *(const f16x8*)(pr + ((lg * 16 + kk * 64) ^ swr));
      }
#pragma unroll
      for (int ct = 0; ct < 2; ++ct)
#pragma unroll
        for (int kk = 0; kk < 2; ++kk)
#pragma unroll
          for (int mt = 0; mt < 4; ++mt)
            acc[ct][mt] = __builtin_amdgcn_mfma_f32_16x16x32_f16(vf[1][ct][kk], pf[mt][kk], acc[ct][mt], 0, 0, 0);
    }

    __syncthreads();   // matched by producer's final-l barrier

    // normalize and write rt fp16 [m][c] (c-contiguous)
    float linv[4];
#pragma unroll
    for (int mt = 0; mt < 4; ++mt) linv[mt] = 1.0f / s_fac[0][mt * 16 + lr];
    _Float16* ob = Rt + bb * (size_t)Nc * Cc;
#pragma unroll
    for (int ct = 0; ct < 2; ++ct)
#pragma unroll
      for (int mt = 0; mt < 4; ++mt) {
        const int c0 = cw * 32 + ct * 16 + lg * 4;
        const int m  = m0 + mt * 16 + lr;
        f16x4 o4;
#pragma unroll
        for (int r = 0; r < 4; ++r) o4[r] = (_Float16)(acc[ct][mt][r] * linv[mt]);
        *(f16x4*)&ob[(size_t)m * Cc + c0] = o4;
      }
  }
}

// ---------------------------------------------------------------------------
// t = w_t @ r via MFMA -> Th fp16 [2B][o][m], plus per-block BN partial sums
// (partials from exact fp32 accumulators). grid (Nc/128, Cc/128, 8)
// ---------------------------------------------------------------------------
__global__ __launch_bounds__(256, 4) void conv_t_mfma_kernel(
    const _Float16* __restrict__ Rt, const _Float16* __restrict__ Wh,
    _Float16* __restrict__ Th, float* __restrict__ part)
{
  __shared__ float red[2][2][4][16][2];
  const int t  = threadIdx.x;
  const int ws = t >> 6, l = t & 63, lr = l & 15, lg = l >> 4;
  const int wm = ws >> 1, wo = ws & 1;
  const int m_w = blockIdx.x * 128 + wm * 64;
  const int o_w = blockIdx.y * 128 + wo * 64;
  const int z  = blockIdx.z, br = z >> 2, b = z & 3;
  const size_t bb = (size_t)(br * Bc + b);

  const _Float16* abase = Rt + (bb * Nc + m_w + lr) * Cc + lg * 8;
  const _Float16* bbase = Wh + ((size_t)(2 + br) * Cc + o_w + lr) * Cc + lg * 8;
  f32x4 acc[4][4] = {};  // [ot][mt]

  for (int c0 = 0; c0 < Cc; c0 += 32) {
    f16x8 af[4], bfr[4];
#pragma unroll
    for (int mt = 0; mt < 4; ++mt)
      af[mt] = *(const f16x8*)(abase + (size_t)(mt * 16) * Cc + c0);
#pragma unroll
    for (int ot = 0; ot < 4; ++ot)
      bfr[ot] = *(const f16x8*)(bbase + (size_t)(ot * 16) * Cc + c0);
#pragma unroll
    for (int ot = 0; ot < 4; ++ot)
#pragma unroll
      for (int mt = 0; mt < 4; ++mt)
        acc[ot][mt] = __builtin_amdgcn_mfma_f32_16x16x32_f16(af[mt], bfr[ot], acc[ot][mt], 0, 0, 0);
  }
  _Float16* Tb = Th + bb * Cc * Nc;
#pragma unroll
  for (int ot = 0; ot < 4; ++ot) {
    float s = 0.f, q = 0.f;
#pragma unroll
    for (int mt = 0; mt < 4; ++mt) {
      const int o = o_w + ot * 16 + lr;
      const int m = m_w + mt * 16 + lg * 4;
      f16x4 h4;
#pragma unroll
      for (int r = 0; r < 4; ++r) {
        float v = acc[ot][mt][r];
        h4[r] = (_Float16)v;
        s += v; q += v * v;
      }
      *(f16x4*)&Tb[(size_t)o * Nc + m] = h4;
    }
    s += __shfl_xor(s, 16); s += __shfl_xor(s, 32);
    q += __shfl_xor(q, 16); q += __shfl_xor(q, 32);
    if (lg == 0) { red[wm][wo][ot][lr][0] = s; red[wm][wo][ot][lr][1] = q; }
  }
  __syncthreads();
  {
    const int wo2 = t >> 7, ot2 = (t >> 5) & 3, lr2 = (t >> 1) & 15, kind = t & 1;
    float v = red[0][wo2][ot2][lr2][kind] + red[1][wo2][ot2][lr2][kind];
    const int c = blockIdx.y * 128 + wo2 * 64 + ot2 * 16 + lr2;
    const int slot = blockIdx.x * 4 + b;
    part[(((size_t)br * Cc + c) * 128 + slot) * 2 + kind] = v;
  }
}

// ---------------------------------------------------------------------------
// finalize BN stats: mean / istd per (br, channel)
// ---------------------------------------------------------------------------
__global__ __launch_bounds__(256) void bn_finalize_kernel(
    const float* __restrict__ part, float* __restrict__ stats)
{
  const int br = blockIdx.x, c = threadIdx.x;
  const float* p = part + ((size_t)br * Cc + c) * 128 * 2;
  float s = 0.f, q = 0.f;
#pragma unroll 4
  for (int i = 0; i < 128; ++i) { s += p[i * 2]; q += p[i * 2 + 1]; }
  const float inv_n = 1.0f / (float)(Bc * Nc);
  const float mean = s * inv_n;
  const float var  = q * inv_n - mean * mean;
  stats[(br * 2 + 0) * Cc + c] = mean;
  stats[(br * 2 + 1) * Cc + c] = rsqrtf(var + 1e-5f);
}

// ---------------------------------------------------------------------------
// Epilogue: OUT = SRC + relu(bn(Th)) -> d_out (fp32)
// ---------------------------------------------------------------------------
__global__ __launch_bounds__(256) void bn_out_kernel(
    const _Float16* __restrict__ Th, float* __restrict__ OUT,
    const float* __restrict__ X, const float* __restrict__ Y,
    const float* __restrict__ stats, const float* __restrict__ gamma,
    const float* __restrict__ beta)
{
  const int br = blockIdx.y;
  const int i = blockIdx.x * 256 + threadIdx.x;
  const size_t flat = ((size_t)i << 2);
  const int c = (int)((flat >> 12) & (Cc - 1));
  float mean = stats[(br * 2 + 0) * Cc + c], istd = stats[(br * 2 + 1) * Cc + c];
  float gm = gamma[c], bt = beta[c];
  const _Float16* Tb = Th + (size_t)br * Bc * Cc * Nc;
  float* Ob = OUT + (size_t)br * Bc * Cc * Nc;
  const float* SRC = (br ? Y : X);
  f16x4 t4 = *(const f16x4*)&Tb[flat];
  float4 s4 = *(const float4*)&SRC[flat];
  float4 o4;
  o4.x = s4.x + fmaxf(0.f, gm * ((float)t4[0] - mean) * istd + bt);
  o4.y = s4.y + fmaxf(0.f, gm * ((float)t4[1] - mean) * istd + bt);
  o4.z = s4.z + fmaxf(0.f, gm * ((float)t4[2] - mean) * istd + bt);
  o4.w = s4.w + fmaxf(0.f, gm * ((float)t4[3] - mean) * istd + bt);
  *(float4*)&Ob[flat] = o4;
}

// ---------------------------------------------------------------------------
extern "C" void kernel_launch(void* const* d_in, const int* in_sizes, int n_in,
                              void* d_out, int out_size, void* d_ws, size_t ws_size,
                              hipStream_t stream) {
  const float* x     = (const float*)d_in[0];
  const float* y     = (const float*)d_in[1];
  const float* w_qkx = (const float*)d_in[2];
  const float* w_vx  = (const float*)d_in[3];
  const float* w_tx  = (const float*)d_in[4];
  const float* w_qky = (const float*)d_in[5];
  const float* w_vy  = (const float*)d_in[6];
  const float* w_ty  = (const float*)d_in[7];
  const float* gamma = (const float*)d_in[8];
  const float* beta  = (const float*)d_in[9];

  float* out = (float*)d_out;  // [2][B][C][N]

  char* wsb = (char*)d_ws;
  _Float16* qt = (_Float16*)wsb;                        // 4 MB  [2B][N][64]
  _Float16* kt = (_Float16*)(wsb + (4ull << 20));       // 4 MB  (pre-swizzled)
  _Float16* vb = (_Float16*)(wsb + (8ull << 20));       // 16 MB [2B][C][N]
  _Float16* xt = (_Float16*)(wsb + (24ull << 20));      // 16 MB [2][B][N][C]
  _Float16* rt = (_Float16*)(wsb + (24ull << 20));      // 16 MB (overlays xt, dead by attn)
  _Float16* th = (_Float16*)(wsb + (40ull << 20));      // 16 MB [2B][C][N] fp16
  _Float16* wh = (_Float16*)(wsb + (56ull << 20));      // 576 KB weights fp16
  float* part  = (float*)(wsb + (56ull << 20) + (640ull << 10));  // 512 KB
  float* st    = (float*)(wsb + (56ull << 20) + (1152ull << 10)); // 4 KB

  wconv_kernel<<<dim3(Cc * Cc / 256, 6), 256, 0, stream>>>(w_vx, w_vy, w_tx, w_ty, w_qkx, w_qky, wh);
  transpose_kernel<<<dim3(Nc / 64, Cc / 64, 8), 256, 0, stream>>>(x, y, xt);
  conv_qk_mfma_kernel<<<dim3(Nc / 128, 2, 8), 256, 0, stream>>>(xt, wh, qt, kt);
  conv_v_mfma_kernel<<<dim3(Nc / 128, Cc / 128, 8), 256, 0, stream>>>(xt, wh, vb);
  attn_mfma_kernel<<<dim3(Nc / 64, 1, 8), 768, 0, stream>>>(qt, kt, vb, rt);
  conv_t_mfma_kernel<<<dim3(Nc / 128, Cc / 128, 8), 256, 0, stream>>>(rt, wh, th, part);
  bn_finalize_kernel<<<2, 256, 0, stream>>>(part, st);
  bn_out_kernel<<<dim3((Bc * Cc * Nc / 4) / 256, 2), 256, 0, stream>>>(th, out, x, y, st, gamma, beta);
}

// Round 20
// 217.145 us; speedup vs baseline: 1.3584x; 1.0612x over previous
//
#include <hip/hip_runtime.h>

constexpr int Bc = 4;     // batch
constexpr int Cc = 256;   // channels
constexpr int Dc = 64;    // q/k dim
constexpr int Nc = 4096;  // sequence length

typedef __attribute__((ext_vector_type(8))) _Float16 f16x8;
typedef __attribute__((ext_vector_type(4))) _Float16 f16x4;
typedef __attribute__((ext_vector_type(4))) float f32x4;

__device__ inline float exp2fast(float x) { return __builtin_amdgcn_exp2f(x); }

// async 16B global->LDS (wave-uniform LDS base, per-lane global addr)
__device__ inline void gload_lds16(const _Float16* g, _Float16* lds) {
  __builtin_amdgcn_global_load_lds(
      (const __attribute__((address_space(1))) unsigned int*)g,
      (__attribute__((address_space(3))) unsigned int*)lds, 16, 0, 0);
}

// ---------------------------------------------------------------------------
// transpose-cast: x,y fp32 [b][c][n] -> Xt fp16 [src][b][n][c], PLUS (z==8)
// weight cast fp32->fp16 into Wh (0..3 = w_vx,w_vy,w_tx,w_ty; 4..5 = w_qk*).
// grid (Nc/64, Cc/64, 9)
// ---------------------------------------------------------------------------
__global__ __launch_bounds__(256) void transpose_kernel(
    const float* __restrict__ X, const float* __restrict__ Y,
    const float* __restrict__ Wvx, const float* __restrict__ Wvy,
    const float* __restrict__ Wtx, const float* __restrict__ Wty,
    const float* __restrict__ Wqkx, const float* __restrict__ Wqky,
    _Float16* __restrict__ Xt, _Float16* __restrict__ Wh)
{
  __shared__ float tile[64][65];
  const int t = threadIdx.x;
  const int z = blockIdx.z;
  if (z == 8) {
    // weight cast: 256 blocks x 256 threads, grid-stride over 294912 elems
    const int gid = (int)((blockIdx.y * gridDim.x + blockIdx.x) * 256 + t);
    const int tot = 4 * Cc * Cc + 2 * Dc * Cc;
    for (int i = gid; i < tot; i += 65536) {
      if (i < 4 * Cc * Cc) {
        const int z2 = i >> 16, idx = i & 65535;
        const float* w = (z2 == 0) ? Wvx : (z2 == 1) ? Wvy : (z2 == 2) ? Wtx : Wty;
        Wh[i] = (_Float16)w[idx];
      } else {
        const int j = i - 4 * Cc * Cc;
        const int z2 = j >> 14, idx = j & 16383;
        const float* w = z2 ? Wqky : Wqkx;
        Wh[i] = (_Float16)w[idx];
      }
    }
    return;
  }
  const int n0 = blockIdx.x * 64;
  const int c0 = blockIdx.y * 64;
  const int br = z >> 2, b = z & 3;
  const float* In = (br ? Y : X) + (size_t)b * Cc * Nc;
#pragma unroll
  for (int p = 0; p < 4; ++p) {
    const int c = p * 16 + (t >> 4), n4 = (t & 15) * 4;
    float4 v = *(const float4*)&In[(size_t)(c0 + c) * Nc + n0 + n4];
    tile[c][n4 + 0] = v.x; tile[c][n4 + 1] = v.y;
    tile[c][n4 + 2] = v.z; tile[c][n4 + 3] = v.w;
  }
  __syncthreads();
  _Float16* Ob = Xt + ((size_t)(br * Bc + b) * Nc + n0) * Cc + c0;
#pragma unroll
  for (int p = 0; p < 4; ++p) {
    const int n = p * 16 + (t >> 4), c4 = (t & 15) * 4;
    f16x4 w;
#pragma unroll
    for (int j = 0; j < 4; ++j) w[j] = (_Float16)tile[c4 + j][n];
    *(f16x4*)&Ob[(size_t)n * Cc + c4] = w;
  }
}

// ---------------------------------------------------------------------------
// q/k conv via MFMA: Out[n][d] = sum_c Wqk[d][c] * Xt[n][c]
// Q is scaled by log2(e) so attention softmax can use exp2 directly.
// K rows PRE-SWIZZLED (half-off ^= (n&7)<<3). grid (Nc/128, 2 {q,k}, 8)
// ---------------------------------------------------------------------------
__global__ __launch_bounds__(256, 4) void conv_qk_mfma_kernel(
    const _Float16* __restrict__ Xt, const _Float16* __restrict__ Wh,
    _Float16* __restrict__ Qt, _Float16* __restrict__ Kt)
{
  const int t  = threadIdx.x;
  const int ws = t >> 6, l = t & 63, lr = l & 15, lg = l >> 4;
  const int n_w = blockIdx.x * 128 + ws * 32;
  const int qk = blockIdx.y;
  const int z  = blockIdx.z, br = z >> 2, b = z & 3;
  const size_t bb = (size_t)(br * Bc + b);
  const int insel = (qk ^ br ^ 1) & 1;   // 0=x, 1=y
  _Float16* Out = qk ? Kt : Qt;
  const float scale = qk ? 1.0f : 1.44269504088896f;

  const _Float16* wbase = Wh + (size_t)4 * Cc * Cc + (size_t)br * Dc * Cc
                          + (size_t)lr * Cc + lg * 8;
  const _Float16* xbase = Xt + ((size_t)(insel * Bc + b) * Nc + n_w + lr) * Cc + lg * 8;

  f32x4 acc[4][2] = {};  // [dt][nt]
  for (int c0 = 0; c0 < Cc; c0 += 32) {
    f16x8 wf[4], xf[2];
#pragma unroll
    for (int dt = 0; dt < 4; ++dt)
      wf[dt] = *(const f16x8*)(wbase + (size_t)(dt * 16) * Cc + c0);
#pragma unroll
    for (int nt = 0; nt < 2; ++nt)
      xf[nt] = *(const f16x8*)(xbase + (size_t)(nt * 16) * Cc + c0);
#pragma unroll
    for (int dt = 0; dt < 4; ++dt)
#pragma unroll
      for (int nt = 0; nt < 2; ++nt)
        acc[dt][nt] = __builtin_amdgcn_mfma_f32_16x16x32_f16(wf[dt], xf[nt], acc[dt][nt], 0, 0, 0);
  }
#pragma unroll
  for (int dt = 0; dt < 4; ++dt)
#pragma unroll
    for (int nt = 0; nt < 2; ++nt) {
      const int n  = n_w + nt * 16 + lr;
      const int d0 = dt * 16 + lg * 4;
      const int off = qk ? (d0 ^ ((n & 7) << 3)) : d0;
      f16x4 o4;
#pragma unroll
      for (int r = 0; r < 4; ++r) o4[r] = (_Float16)(acc[dt][nt][r] * scale);
      *(f16x4*)&Out[(bb * Nc + n) * 64 + off] = o4;
    }
}

// ---------------------------------------------------------------------------
// v conv via MFMA: V[cout][n] = sum_c Wv[cout][c] * Xt[n][c]
// grid (Nc/128, Cc/128, 8), block 256 (2x2 wave grid)
// ---------------------------------------------------------------------------
__global__ __launch_bounds__(256, 4) void conv_v_mfma_kernel(
    const _Float16* __restrict__ Xt, const _Float16* __restrict__ Wh,
    _Float16* __restrict__ Vb)
{
  const int t  = threadIdx.x;
  const int ws = t >> 6, l = t & 63, lr = l & 15, lg = l >> 4;
  const int wm = ws >> 1, wo = ws & 1;
  const int n_w = blockIdx.x * 128 + wm * 64;
  const int o_w = blockIdx.y * 128 + wo * 64;
  const int z  = blockIdx.z, br = z >> 2, b = z & 3;
  const size_t bb = (size_t)(br * Bc + b);

  const _Float16* abase = Xt + (bb * Nc + n_w + lr) * Cc + lg * 8;
  const _Float16* bbase = Wh + ((size_t)br * Cc + o_w + lr) * Cc + lg * 8;
  f32x4 acc[4][4] = {};  // [ot][mt]

  for (int c0 = 0; c0 < Cc; c0 += 32) {
    f16x8 af[4], bfr[4];
#pragma unroll
    for (int mt = 0; mt < 4; ++mt)
      af[mt] = *(const f16x8*)(abase + (size_t)(mt * 16) * Cc + c0);
#pragma unroll
    for (int ot = 0; ot < 4; ++ot)
      bfr[ot] = *(const f16x8*)(bbase + (size_t)(ot * 16) * Cc + c0);
#pragma unroll
    for (int ot = 0; ot < 4; ++ot)
#pragma unroll
      for (int mt = 0; mt < 4; ++mt)
        acc[ot][mt] = __builtin_amdgcn_mfma_f32_16x16x32_f16(af[mt], bfr[ot], acc[ot][mt], 0, 0, 0);
  }
#pragma unroll
  for (int ot = 0; ot < 4; ++ot)
#pragma unroll
    for (int mt = 0; mt < 4; ++mt) {
      const int cout = o_w + ot * 16 + lr;
      const int n = n_w + mt * 16 + lg * 4;
      f16x4 o4;
#pragma unroll
      for (int r = 0; r < 4; ++r) o4[r] = (_Float16)acc[ot][mt][r];
      *(f16x4*)&Vb[(bb * Cc + cout) * Nc + n] = o4;
    }
}

// ---------------------------------------------------------------------------
// MFMA flash attention, wave-specialized, NO KV-split (r19 proven kernel):
// producers ws 0-3 (K staging dbuf + QK + defer-max softmax + P/s_fac),
// consumers ws 4-11 (32-ch strip, V parity prefetch + PV, in-kernel
// normalize via producer's final l through s_fac[0]). grid (Nc/64, 1, 8).
// ---------------------------------------------------------------------------
__global__ __launch_bounds__(768, 3) void attn_mfma_kernel(
    const _Float16* __restrict__ Qt,   // [2B][N][64], pre-scaled by log2(e)
    const _Float16* __restrict__ Kt,   // [2B][N][64] pre-swizzled rows
    const _Float16* __restrict__ V,    // [2B][C][N]
    _Float16* __restrict__ Rt)         // [2B][N][C] normalized output
{
  __shared__ __align__(16) _Float16 k_lds[2][64 * 64];  // 2 x 8KB
  __shared__ __align__(16) _Float16 p_lds[2][64 * 64];  // 2 x 8KB
  __shared__ float s_fac[2][64];       // s_fac[0] doubles as final-l channel

  const int t  = threadIdx.x;
  const int ws = t >> 6;          // 0..11
  const int l  = t & 63;
  const int lr = l & 15;
  const int lg = l >> 4;

  // XCD-aware bijective remap (nwg = 512, divisible by 8)
  const int nwg  = (Nc / 64) * 8;
  const int lin  = blockIdx.x + gridDim.x * blockIdx.z;
  const int work = (lin & 7) * (nwg >> 3) + (lin >> 3);
  const int m0   = (work & 63) * 64;
  const size_t bb = (size_t)(work >> 6);

  const _Float16* kgl = Kt + bb * Nc * 64;
  const int nch = Nc >> 6;   // 64 chunks, even

  if (ws < 4) {
    // ================= PRODUCER: QK + softmax =================
    const _Float16* qp = Qt + (bb * Nc + m0 + ws * 16 + lr) * 64 + lg * 8;
    const f16x8 qf0 = *(const f16x8*)qp;
    const f16x8 qf1 = *(const f16x8*)(qp + 32);
    const _Float16* gq = kgl + ws * 512 + l * 8;

    float m_run = -1e30f, l_run = 0.f;   // per-lane partial l
    const int mrow = ws * 16 + lr;
    const int sw   = (mrow & 7) << 4;

    {  // prologue: chunk 0 -> k_lds[0]
#pragma unroll
      for (int r = 0; r < 2; ++r)
        gload_lds16(gq + r * 2048, &k_lds[0][ws * 512 + r * 2048]);
    }
    __syncthreads();

    for (int ch2 = 0; ch2 < nch; ch2 += 2) {
#pragma unroll
      for (int par = 0; par < 2; ++par) {
        const int ch = ch2 + par;
        // stage K(ch+1) into k_lds[par^1]
        if (ch + 1 < nch) {
          const _Float16* g = gq + (size_t)(ch + 1) * (64 * 64);
#pragma unroll
          for (int r = 0; r < 2; ++r)
            gload_lds16(g + r * 2048, &k_lds[par ^ 1][ws * 512 + r * 2048]);
        }
        // QK^T for chunk ch from k_lds[par]
        f32x4 st[4] = {};
#pragma unroll
        for (int nt = 0; nt < 4; ++nt) {
          const int   krow = nt * 16 + lr;
          const char* krp  = (const char*)&k_lds[par][krow * 64];
          const int   swr  = (krow & 7) << 4;
          f16x8 kh0 = *(const f16x8*)(krp + ((lg * 16) ^ swr));
          f16x8 kh1 = *(const f16x8*)(krp + ((64 + lg * 16) ^ swr));
          st[nt] = __builtin_amdgcn_mfma_f32_16x16x32_f16(kh0, qf0, st[nt], 0, 0, 0);
          st[nt] = __builtin_amdgcn_mfma_f32_16x16x32_f16(kh1, qf1, st[nt], 0, 0, 0);
        }
        // defer-max softmax (zero cross-lane steady state)
        float mx = st[0][0];
#pragma unroll
        for (int nt = 0; nt < 4; ++nt)
#pragma unroll
          for (int rr = 0; rr < 4; ++rr) mx = fmaxf(mx, st[nt][rr]);
        float s = 1.0f;
        if (__any(mx > m_run + 12.0f)) {
          mx = fmaxf(mx, __shfl_xor(mx, 16));
          mx = fmaxf(mx, __shfl_xor(mx, 32));
          const float mnew = fmaxf(m_run, mx);
          s = exp2fast(m_run - mnew);
          m_run = mnew;
        }
        float sum = 0.f;
        float p[4][4];
#pragma unroll
        for (int nt = 0; nt < 4; ++nt)
#pragma unroll
          for (int rr = 0; rr < 4; ++rr) {
            p[nt][rr] = exp2fast(st[nt][rr] - m_run);
            sum += p[nt][rr];
          }
        l_run = l_run * s + sum;
        {
          char* prow = (char*)&p_lds[par][mrow * 64];
#pragma unroll
          for (int nt = 0; nt < 4; ++nt) {
            f16x4 pb;
            pb[0] = (_Float16)p[nt][0]; pb[1] = (_Float16)p[nt][1];
            pb[2] = (_Float16)p[nt][2]; pb[3] = (_Float16)p[nt][3];
            *(f16x4*)(prow + ((nt * 32 + lg * 8) ^ sw)) = pb;
          }
        }
        if (lg == 0) s_fac[par][ws * 16 + lr] = s;
        __syncthreads();
      }
    }

    // epilogue: reduce per-lane partial l, hand final l to consumers
    l_run += __shfl_xor(l_run, 16);
    l_run += __shfl_xor(l_run, 32);
    if (lg == 0) s_fac[0][mrow] = l_run;
    __syncthreads();   // matched by consumer's final barrier
  } else {
    // ================= CONSUMER: PV (32-channel strip per wave) ============
    const int cw = ws - 4;   // 0..7
    const _Float16* vbase = V + (bb * Cc + cw * 32 + lr) * Nc + lg * 8;
    f32x4 acc[2][4] = {};
    f16x8 vf[2][2][2];   // [parity][ct][kk]

    __syncthreads();   // match producer prologue barrier

    for (int ch2 = 0; ch2 < nch; ch2 += 2) {
#pragma unroll
      for (int par = 0; par < 2; ++par) {
        const int ch = ch2 + par;
        // V prefetch for chunk ch (consumed next sub-iter)
        {
          const _Float16* vp = vbase + ch * 64;
#pragma unroll
          for (int ct = 0; ct < 2; ++ct)
#pragma unroll
            for (int kk = 0; kk < 2; ++kk)
              vf[par][ct][kk] = *(const f16x8*)(vp + (size_t)ct * 16 * Nc + kk * 32);
        }
        // PV for chunk ch-1 (p_lds/s_fac from par^1; vf[par^1])
        if (ch > 0) {
          float scm[4];
#pragma unroll
          for (int mt = 0; mt < 4; ++mt) scm[mt] = s_fac[par ^ 1][mt * 16 + lr];
          const int needs = (scm[0] != 1.f) | (scm[1] != 1.f) |
                            (scm[2] != 1.f) | (scm[3] != 1.f);
          if (__any(needs)) {
#pragma unroll
            for (int ct = 0; ct < 2; ++ct)
#pragma unroll
              for (int mt = 0; mt < 4; ++mt) {
                acc[ct][mt][0] *= scm[mt]; acc[ct][mt][1] *= scm[mt];
                acc[ct][mt][2] *= scm[mt]; acc[ct][mt][3] *= scm[mt];
              }
          }
          f16x8 pf[4][2];
#pragma unroll
          for (int mt = 0; mt < 4; ++mt) {
            const int   rm  = mt * 16 + lr;
            const char* pr  = (const char*)&p_lds[par ^ 1][rm * 64];
            const int   swr = (rm & 7) << 4;
#pragma unroll
            for (int kk = 0; kk < 2; ++kk)
              pf[mt][kk] = *(const f16x8*)(pr + ((lg * 16 + kk * 64) ^ swr));
          }
          __builtin_amdgcn_s_setprio(1);
#pragma unroll
          for (int ct = 0; ct < 2; ++ct)
#pragma unroll
            for (int kk = 0; kk < 2; ++kk)
#pragma unroll
              for (int mt = 0; mt < 4; ++mt)
                acc[ct][mt] = __builtin_amdgcn_mfma_f32_16x16x32_f16(vf[par ^ 1][ct][kk], pf[mt][kk], acc[ct][mt], 0, 0, 0);
          __builtin_amdgcn_s_setprio(0);
        }
        __syncthreads();
      }
    }

    // epilogue PV (last chunk: parity 1, nch even)
    {
      float scm[4];
#pragma unroll
      for (int mt = 0; mt < 4; ++mt) scm[mt] = s_fac[1][mt * 16 + lr];
      const int needs = (scm[0] != 1.f) | (scm[1] != 1.f) |
                        (scm[2] != 1.f) | (scm[3] != 1.f);
      if (__any(needs)) {
#pragma unroll
        for (int ct = 0; ct < 2; ++ct)
#pragma unroll
          for (int mt = 0; mt < 4; ++mt) {
            acc[ct][mt][0] *= scm[mt]; acc[ct][mt][1] *= scm[mt];
            acc[ct][mt][2] *= scm[mt]; acc[ct][mt][3] *= scm[mt];
          }
      }
      f16x8 pf[4][2];
#pragma unroll
      for (int mt = 0; mt < 4; ++mt) {
        const int   rm  = mt * 16 + lr;
        const char* pr  = (const char*)&p_lds[1][rm * 64];
        const int   swr = (rm & 7) << 4;
#pragma unroll
        for (int kk = 0; kk < 2; ++kk)
          pf[mt][kk] = *(const f16x8*)(pr + ((lg * 16 + kk * 64) ^ swr));
      }
#pragma unroll
      for (int ct = 0; ct < 2; ++ct)
#pragma unroll
        for (int kk = 0; kk < 2; ++kk)
#pragma unroll
          for (int mt = 0; mt < 4; ++mt)
            acc[ct][mt] = __builtin_amdgcn_mfma_f32_16x16x32_f16(vf[1][ct][kk], pf[mt][kk], acc[ct][mt], 0, 0, 0);
    }

    __syncthreads();   // matched by producer's final-l barrier

    // normalize and write rt fp16 [m][c] (c-contiguous)
    float linv[4];
#pragma unroll
    for (int mt = 0; mt < 4; ++mt) linv[mt] = 1.0f / s_fac[0][mt * 16 + lr];
    _Float16* ob = Rt + bb * (size_t)Nc * Cc;
#pragma unroll
    for (int ct = 0; ct < 2; ++ct)
#pragma unroll
      for (int mt = 0; mt < 4; ++mt) {
        const int c0 = cw * 32 + ct * 16 + lg * 4;
        const int m  = m0 + mt * 16 + lr;
        f16x4 o4;
#pragma unroll
        for (int r = 0; r < 4; ++r) o4[r] = (_Float16)(acc[ct][mt][r] * linv[mt]);
        *(f16x4*)&ob[(size_t)m * Cc + c0] = o4;
      }
  }
}

// ---------------------------------------------------------------------------
// t = w_t @ r via MFMA -> Th fp16 [2B][o][m], plus per-block BN partial sums
// (partials from exact fp32 accumulators). grid (Nc/128, Cc/128, 8)
// ---------------------------------------------------------------------------
__global__ __launch_bounds__(256, 4) void conv_t_mfma_kernel(
    const _Float16* __restrict__ Rt, const _Float16* __restrict__ Wh,
    _Float16* __restrict__ Th, float* __restrict__ part)
{
  __shared__ float red[2][2][4][16][2];
  const int t  = threadIdx.x;
  const int ws = t >> 6, l = t & 63, lr = l & 15, lg = l >> 4;
  const int wm = ws >> 1, wo = ws & 1;
  const int m_w = blockIdx.x * 128 + wm * 64;
  const int o_w = blockIdx.y * 128 + wo * 64;
  const int z  = blockIdx.z, br = z >> 2, b = z & 3;
  const size_t bb = (size_t)(br * Bc + b);

  const _Float16* abase = Rt + (bb * Nc + m_w + lr) * Cc + lg * 8;
  const _Float16* bbase = Wh + ((size_t)(2 + br) * Cc + o_w + lr) * Cc + lg * 8;
  f32x4 acc[4][4] = {};  // [ot][mt]

  for (int c0 = 0; c0 < Cc; c0 += 32) {
    f16x8 af[4], bfr[4];
#pragma unroll
    for (int mt = 0; mt < 4; ++mt)
      af[mt] = *(const f16x8*)(abase + (size_t)(mt * 16) * Cc + c0);
#pragma unroll
    for (int ot = 0; ot < 4; ++ot)
      bfr[ot] = *(const f16x8*)(bbase + (size_t)(ot * 16) * Cc + c0);
#pragma unroll
    for (int ot = 0; ot < 4; ++ot)
#pragma unroll
      for (int mt = 0; mt < 4; ++mt)
        acc[ot][mt] = __builtin_amdgcn_mfma_f32_16x16x32_f16(af[mt], bfr[ot], acc[ot][mt], 0, 0, 0);
  }
  _Float16* Tb = Th + bb * Cc * Nc;
#pragma unroll
  for (int ot = 0; ot < 4; ++ot) {
    float s = 0.f, q = 0.f;
#pragma unroll
    for (int mt = 0; mt < 4; ++mt) {
      const int o = o_w + ot * 16 + lr;
      const int m = m_w + mt * 16 + lg * 4;
      f16x4 h4;
#pragma unroll
      for (int r = 0; r < 4; ++r) {
        float v = acc[ot][mt][r];
        h4[r] = (_Float16)v;
        s += v; q += v * v;
      }
      *(f16x4*)&Tb[(size_t)o * Nc + m] = h4;
    }
    s += __shfl_xor(s, 16); s += __shfl_xor(s, 32);
    q += __shfl_xor(q, 16); q += __shfl_xor(q, 32);
    if (lg == 0) { red[wm][wo][ot][lr][0] = s; red[wm][wo][ot][lr][1] = q; }
  }
  __syncthreads();
  {
    const int wo2 = t >> 7, ot2 = (t >> 5) & 3, lr2 = (t >> 1) & 15, kind = t & 1;
    float v = red[0][wo2][ot2][lr2][kind] + red[1][wo2][ot2][lr2][kind];
    const int c = blockIdx.y * 128 + wo2 * 64 + ot2 * 16 + lr2;
    const int slot = blockIdx.x * 4 + b;
    part[(((size_t)br * Cc + c) * 128 + slot) * 2 + kind] = v;
  }
}

// ---------------------------------------------------------------------------
// Epilogue: per-block BN-stat reduction (each block covers exactly ONE
// channel: 1024 contiguous elems < Nc) + OUT = SRC + relu(bn(Th)).
// grid ((B*C*N/4)/256, 2)
// ---------------------------------------------------------------------------
__global__ __launch_bounds__(256) void bn_out_kernel(
    const _Float16* __restrict__ Th, float* __restrict__ OUT,
    const float* __restrict__ X, const float* __restrict__ Y,
    const float* __restrict__ part, const float* __restrict__ gamma,
    const float* __restrict__ beta)
{
  __shared__ float red2[4][2];
  __shared__ float mi[2];
  const int br = blockIdx.y;
  const int t  = threadIdx.x;
  const int i  = blockIdx.x * 256 + t;
  const size_t flat = ((size_t)i << 2);
  const int c = (int)((flat >> 12) & (Cc - 1));   // constant per block

  // in-block BN stats for channel c: 256 part values (slot*2+kind layout)
  float v = part[((size_t)br * Cc + c) * 256 + t];
#pragma unroll
  for (int off = 2; off <= 32; off <<= 1) v += __shfl_xor(v, off);
  if ((t & 63) < 2) red2[t >> 6][t & 1] = v;
  __syncthreads();
  if (t == 0) {
    float s = red2[0][0] + red2[1][0] + red2[2][0] + red2[3][0];
    float q = red2[0][1] + red2[1][1] + red2[2][1] + red2[3][1];
    const float inv_n = 1.0f / (float)(Bc * Nc);
    const float mean = s * inv_n;
    const float var  = q * inv_n - mean * mean;
    mi[0] = mean;
    mi[1] = rsqrtf(var + 1e-5f);
  }
  __syncthreads();
  const float mean = mi[0], istd = mi[1];
  const float gm = gamma[c], bt = beta[c];

  const _Float16* Tb = Th + (size_t)br * Bc * Cc * Nc;
  float* Ob = OUT + (size_t)br * Bc * Cc * Nc;
  const float* SRC = (br ? Y : X);
  f16x4 t4 = *(const f16x4*)&Tb[flat];
  float4 s4 = *(const float4*)&SRC[flat];
  float4 o4;
  o4.x = s4.x + fmaxf(0.f, gm * ((float)t4[0] - mean) * istd + bt);
  o4.y = s4.y + fmaxf(0.f, gm * ((float)t4[1] - mean) * istd + bt);
  o4.z = s4.z + fmaxf(0.f, gm * ((float)t4[2] - mean) * istd + bt);
  o4.w = s4.w + fmaxf(0.f, gm * ((float)t4[3] - mean) * istd + bt);
  *(float4*)&Ob[flat] = o4;
}

// ---------------------------------------------------------------------------
extern "C" void kernel_launch(void* const* d_in, const int* in_sizes, int n_in,
                              void* d_out, int out_size, void* d_ws, size_t ws_size,
                              hipStream_t stream) {
  const float* x     = (const float*)d_in[0];
  const float* y     = (const float*)d_in[1];
  const float* w_qkx = (const float*)d_in[2];
  const float* w_vx  = (const float*)d_in[3];
  const float* w_tx  = (const float*)d_in[4];
  const float* w_qky = (const float*)d_in[5];
  const float* w_vy  = (const float*)d_in[6];
  const float* w_ty  = (const float*)d_in[7];
  const float* gamma = (const float*)d_in[8];
  const float* beta  = (const float*)d_in[9];

  float* out = (float*)d_out;  // [2][B][C][N]

  char* wsb = (char*)d_ws;
  _Float16* qt = (_Float16*)wsb;                        // 4 MB  [2B][N][64]
  _Float16* kt = (_Float16*)(wsb + (4ull << 20));       // 4 MB  (pre-swizzled)
  _Float16* vb = (_Float16*)(wsb + (8ull << 20));       // 16 MB [2B][C][N]
  _Float16* xt = (_Float16*)(wsb + (24ull << 20));      // 16 MB [2][B][N][C]
  _Float16* rt = (_Float16*)(wsb + (24ull << 20));      // 16 MB (overlays xt, dead by attn)
  _Float16* th = (_Float16*)(wsb + (40ull << 20));      // 16 MB [2B][C][N] fp16
  _Float16* wh = (_Float16*)(wsb + (56ull << 20));      // 576 KB weights fp16
  float* part  = (float*)(wsb + (56ull << 20) + (640ull << 10));  // 512 KB

  transpose_kernel<<<dim3(Nc / 64, Cc / 64, 9), 256, 0, stream>>>(
      x, y, w_vx, w_vy, w_tx, w_ty, w_qkx, w_qky, xt, wh);
  conv_qk_mfma_kernel<<<dim3(Nc / 128, 2, 8), 256, 0, stream>>>(xt, wh, qt, kt);
  conv_v_mfma_kernel<<<dim3(Nc / 128, Cc / 128, 8), 256, 0, stream>>>(xt, wh, vb);
  attn_mfma_kernel<<<dim3(Nc / 64, 1, 8), 768, 0, stream>>>(qt, kt, vb, rt);
  conv_t_mfma_kernel<<<dim3(Nc / 128, Cc / 128, 8), 256, 0, stream>>>(rt, wh, th, part);
  bn_out_kernel<<<dim3((Bc * Cc * Nc / 4) / 256, 2), 256, 0, stream>>>(
      th, out, x, y, part, gamma, beta);
}